// Round 1
// baseline (5746.278 us; speedup 1.0000x reference)
//
#include <hip/hip_runtime.h>
#include <hip/hip_bf16.h>

#define BB 16
#define CC 192
#define HH 96
#define WWW 96
#define HWSZ 9216
#define DKC 64

typedef __hip_bfloat16 bf16;

__device__ __forceinline__ float bf2f(unsigned short u) {
  union { unsigned int i; float f; } x; x.i = ((unsigned int)u) << 16; return x.f;
}

// ---------------- prep: w_out [oc][c][ky][kx] -> wT [c][ky][kx][oc] ----------------
__global__ __launch_bounds__(256) void prep_wT_kernel(const float* __restrict__ w_out,
                                                      float* __restrict__ wT) {
  int e = blockIdx.x * 256 + threadIdx.x;
  if (e >= CC * CC * 9) return;
  int oc = e % CC;
  int r = e / CC;
  int kx = r % 3; r /= 3;
  int ky = r % 3;
  int c = r / 3;
  wT[e] = w_out[((oc * CC + c) * 3 + ky) * 3 + kx];
}

// ---------------- QKV projection: 576 output rows x 64-pixel tiles ----------------
__global__ __launch_bounds__(256) void qkv_kernel(
    const float* __restrict__ x,
    const float* __restrict__ wq, const float* __restrict__ bq,
    const float* __restrict__ wk, const float* __restrict__ bk,
    const float* __restrict__ wv, const float* __restrict__ bv,
    bf16* __restrict__ q, bf16* __restrict__ k, bf16* __restrict__ v) {
  __shared__ float xt[CC][64];
  int b = blockIdx.x / 144;
  int tile = blockIdx.x % 144;
  int pix0 = tile * 64;
  const float* xb = x + (size_t)b * CC * HWSZ + pix0;
  for (int e = threadIdx.x; e < CC * 16; e += 256) {
    int c = e >> 4, seg = e & 15;
    float4 t4 = *(const float4*)(xb + (size_t)c * HWSZ + seg * 4);
    xt[c][seg * 4 + 0] = t4.x; xt[c][seg * 4 + 1] = t4.y;
    xt[c][seg * 4 + 2] = t4.z; xt[c][seg * 4 + 3] = t4.w;
  }
  __syncthreads();
  int lane = threadIdx.x & 63;
  int wid = threadIdx.x >> 6;
  for (int rb = 0; rb < 144; rb += 4) {
    int ro = wid * 144 + rb;                 // 4-row blocks never cross q/k/v boundary
    int tsel = ro / CC, oc = ro % CC;
    const float* Wt = (tsel == 0 ? wq : tsel == 1 ? wk : wv) + (size_t)oc * CC;
    const float* Bt = (tsel == 0 ? bq : tsel == 1 ? bk : bv) + oc;
    bf16* Ot = (tsel == 0 ? q : tsel == 1 ? k : v) + ((size_t)b * CC + oc) * HWSZ + pix0 + lane;
    float a0 = 0.f, a1 = 0.f, a2 = 0.f, a3 = 0.f;
    for (int c = 0; c < CC; c += 4) {
      float x0 = xt[c][lane], x1 = xt[c + 1][lane], x2 = xt[c + 2][lane], x3 = xt[c + 3][lane];
      float4 w0 = *(const float4*)(Wt + c);
      float4 w1 = *(const float4*)(Wt + CC + c);
      float4 w2 = *(const float4*)(Wt + 2 * CC + c);
      float4 w3 = *(const float4*)(Wt + 3 * CC + c);
      a0 += x0 * w0.x + x1 * w0.y + x2 * w0.z + x3 * w0.w;
      a1 += x0 * w1.x + x1 * w1.y + x2 * w1.z + x3 * w1.w;
      a2 += x0 * w2.x + x1 * w2.y + x2 * w2.z + x3 * w2.w;
      a3 += x0 * w3.x + x1 * w3.y + x2 * w3.z + x3 * w3.w;
    }
    Ot[0]            = __float2bfloat16(a0 + Bt[0]);
    Ot[(size_t)HWSZ]     = __float2bfloat16(a1 + Bt[1]);
    Ot[(size_t)2 * HWSZ] = __float2bfloat16(a2 + Bt[2]);
    Ot[(size_t)3 * HWSZ] = __float2bfloat16(a3 + Bt[3]);
  }
}

// ---------------- scores: P x P dots over D, each q/k element read once ----------------
template <int HS, int WS, int OH, int OW, int IDX>
__global__ __launch_bounds__(256) void scores_kernel(
    const bf16* __restrict__ q, const bf16* __restrict__ k, float* __restrict__ scores) {
  constexpr int P = HS * WS;
  constexpr int PAIRS = P * P;
  constexpr int NPOS = DKC * OH * OW;     // = D, divisible by 2048 for all strides
  constexpr int NB = 16;
  constexpr int NSUB = (256 / PAIRS) < 1 ? 1 : (256 / PAIRS);
  __shared__ float qt[128][P];
  __shared__ float kt[128][P];
  int b = blockIdx.x / NB;
  int blk = blockIdx.x % NB;
  const bf16* qb = q + ((size_t)b * CC + IDX * DKC) * HWSZ;
  const bf16* kb = k + ((size_t)b * CC + IDX * DKC) * HWSZ;
  int pr = threadIdx.x % PAIRS;
  int sub = threadIdx.x / PAIRS;
  int pi = pr / P, qi = pr % P;
  float acc = 0.f;
  for (int pos0 = blk * 128; pos0 < NPOS; pos0 += NB * 128) {
    for (int e = threadIdx.x; e < 128 * P; e += 256) {
      int pos = e / P, pp = e % P;
      int posg = pos0 + pos;
      int cl = posg / (OH * OW);
      int rem = posg % (OH * OW);
      int r = rem / OW, s = rem % OW;
      int i = pp / WS, j = pp % WS;
      int off = cl * HWSZ + (r * HS + i) * WWW + s * WS + j;
      qt[pos][pp] = __bfloat162float(qb[off]);
      kt[pos][pp] = __bfloat162float(kb[off]);
    }
    __syncthreads();
    if (sub < NSUB) {
      for (int pos = sub; pos < 128; pos += NSUB)
        acc += qt[pos][pi] * kt[pos][qi];
    }
    __syncthreads();
  }
  if (sub < NSUB) atomicAdd(scores + ((IDX * BB + b) * 256 + pr), acc);
}

// ---------------- softmax over P (scaled by 1/sqrt(D)) ----------------
__global__ void softmax_kernel(const float* __restrict__ scores, float* __restrict__ probs) {
  int t = threadIdx.x;
  int idx, b, p, P; float scale;
  if (t < 64)       { idx = 0; b = t >> 2;           p = t & 3;         P = 4;  scale = 1.f / 384.f; }
  else if (t < 208) { int u = t - 64;  idx = 1; b = u / 9;  p = u % 9;  P = 9;  scale = 1.f / 256.f; }
  else if (t < 464) { int u = t - 208; idx = 2; b = u >> 4; p = u & 15; P = 16; scale = 1.f / 192.f; }
  else return;
  const float* row = scores + (idx * BB + b) * 256 + p * P;
  float* orow = probs + (idx * BB + b) * 256 + p * P;
  float vals[16];
  float m = -1e30f;
  for (int i = 0; i < P; i++) { vals[i] = row[i] * scale; m = fmaxf(m, vals[i]); }
  float s = 0.f;
  for (int i = 0; i < P; i++) { vals[i] = expf(vals[i] - m); s += vals[i]; }
  float inv = 1.f / s;
  for (int i = 0; i < P; i++) orow[i] = vals[i] * inv;
}

// ---------------- PV + unstitch: one (b, channel) plane per block ----------------
template <int HS, int WS, int OH, int OW, int IDX>
__global__ __launch_bounds__(256) void pv_kernel(
    const bf16* __restrict__ v, const float* __restrict__ probs, bf16* __restrict__ attn) {
  constexpr int P = HS * WS;
  __shared__ unsigned short vl[HWSZ];
  __shared__ float pl[P * P];
  int b = blockIdx.x / DKC;
  int cl = blockIdx.x % DKC;
  const bf16* vb = v + ((size_t)b * CC + IDX * DKC + cl) * HWSZ;
  for (int e = threadIdx.x; e < HWSZ / 4; e += 256)
    ((uint2*)vl)[e] = ((const uint2*)vb)[e];
  if (threadIdx.x < P * P) pl[threadIdx.x] = probs[(IDX * BB + b) * 256 + threadIdx.x];
  __syncthreads();
  bf16* ob = attn + ((size_t)b * CC + IDX * DKC + cl) * HWSZ;
  for (int pid = threadIdx.x; pid < HWSZ; pid += 256) {
    int h = pid / WWW, w = pid % WWW;
    int i = h / OH, r = h % OH;       // unstitch: H = i*OH + r
    int j = w / OW, s = w % OW;       //           W = j*OW + s
    int p = i * WS + j;
    float acc = 0.f;
    #pragma unroll
    for (int iq = 0; iq < HS; iq++)
      #pragma unroll
      for (int jq = 0; jq < WS; jq++)
        acc += pl[p * P + iq * WS + jq] * bf2f(vl[(r * HS + iq) * WWW + s * WS + jq]);
    ob[pid] = __float2bfloat16(acc);
  }
}

// ---------------- 3x3 conv + bias + BN partial sums ----------------
__global__ __launch_bounds__(256) void conv_kernel(
    const bf16* __restrict__ attn, const float* __restrict__ wT,
    const float* __restrict__ b_out, float* __restrict__ y,
    float* __restrict__ bnsum, float* __restrict__ bnsqs) {
  __shared__ unsigned short li[3][48][112];   // payload at cols 8..103, halo zeros at 7 and 104
  int oct = blockIdx.x % 3;
  int h = (blockIdx.x / 3) % HH;
  int b = blockIdx.x / (3 * HH);
  int w0 = threadIdx.x & 31;
  int ocg = threadIdx.x >> 5;
  float acc[3][8];
  #pragma unroll
  for (int wi = 0; wi < 3; wi++)
    #pragma unroll
    for (int o = 0; o < 8; o++) acc[wi][o] = 0.f;
  for (int ci = 0; ci < 4; ci++) {
    __syncthreads();
    for (int e = threadIdx.x; e < 3 * 48; e += 256) {
      int ky = e / 48, cc2 = e % 48;
      li[ky][cc2][7] = 0; li[ky][cc2][104] = 0;
    }
    for (int e = threadIdx.x; e < 3 * 48 * 12; e += 256) {
      int ky = e / (48 * 12);
      int cc2 = (e / 12) % 48;
      int seg = e % 12;
      int hr = h + ky - 1;
      uint4 val = make_uint4(0u, 0u, 0u, 0u);
      if (hr >= 0 && hr < HH)
        val = *(const uint4*)(attn + ((size_t)b * CC + ci * 48 + cc2) * HWSZ + hr * WWW + seg * 8);
      *(uint4*)&li[ky][cc2][8 + seg * 8] = val;
    }
    __syncthreads();
    for (int cc = 0; cc < 48; cc++) {
      #pragma unroll
      for (int ky = 0; ky < 3; ky++) {
        const float* wp = wT + (size_t)(((ci * 48 + cc) * 3 + ky) * 3) * CC + oct * 64 + ocg * 8;
        float4 wa0 = *(const float4*)(wp);
        float4 wa1 = *(const float4*)(wp + 4);
        float4 wb0 = *(const float4*)(wp + CC);
        float4 wb1 = *(const float4*)(wp + CC + 4);
        float4 wc0 = *(const float4*)(wp + 2 * CC);
        float4 wc1 = *(const float4*)(wp + 2 * CC + 4);
        #pragma unroll
        for (int wi = 0; wi < 3; wi++) {
          int wc = 8 + w0 + wi * 32;
          float xm = bf2f(li[ky][cc][wc - 1]);
          float xc = bf2f(li[ky][cc][wc]);
          float xp = bf2f(li[ky][cc][wc + 1]);
          acc[wi][0] += xm * wa0.x + xc * wb0.x + xp * wc0.x;
          acc[wi][1] += xm * wa0.y + xc * wb0.y + xp * wc0.y;
          acc[wi][2] += xm * wa0.z + xc * wb0.z + xp * wc0.z;
          acc[wi][3] += xm * wa0.w + xc * wb0.w + xp * wc0.w;
          acc[wi][4] += xm * wa1.x + xc * wb1.x + xp * wc1.x;
          acc[wi][5] += xm * wa1.y + xc * wb1.y + xp * wc1.y;
          acc[wi][6] += xm * wa1.z + xc * wb1.z + xp * wc1.z;
          acc[wi][7] += xm * wa1.w + xc * wb1.w + xp * wc1.w;
        }
      }
    }
  }
  float s1[8], s2[8];
  #pragma unroll
  for (int o = 0; o < 8; o++) { s1[o] = 0.f; s2[o] = 0.f; }
  #pragma unroll
  for (int o = 0; o < 8; o++) {
    int oc = oct * 64 + ocg * 8 + o;
    float bias = b_out[oc];
    float* yp = y + ((size_t)b * CC + oc) * HWSZ + h * WWW + w0;
    #pragma unroll
    for (int wi = 0; wi < 3; wi++) {
      float val = acc[wi][o] + bias;
      yp[wi * 32] = val;
      s1[o] += val; s2[o] += val * val;
    }
  }
  #pragma unroll
  for (int o = 0; o < 8; o++) {
    for (int off = 16; off > 0; off >>= 1) {
      s1[o] += __shfl_down(s1[o], off, 32);
      s2[o] += __shfl_down(s2[o], off, 32);
    }
  }
  if (w0 == 0) {
    int ocb = oct * 64 + ocg * 8;
    #pragma unroll
    for (int o = 0; o < 8; o++) {
      atomicAdd(bnsum + ocb + o, s1[o]);
      atomicAdd(bnsqs + ocb + o, s2[o]);
    }
  }
}

// ---------------- BN finalize ----------------
__global__ void bnfin_kernel(const float* __restrict__ bnsum, const float* __restrict__ bnsqs,
                             const float* __restrict__ gamma, const float* __restrict__ beta,
                             float* __restrict__ scale, float* __restrict__ shift) {
  int c = threadIdx.x;
  if (c >= CC) return;
  const float n = 16.f * 9216.f;
  float mean = bnsum[c] / n;
  float var = bnsqs[c] / n - mean * mean;
  float inv = rsqrtf(var + 1e-5f);
  float sc = gamma[c] * inv;
  scale[c] = sc;
  shift[c] = beta[c] - mean * sc;
}

// ---------------- BN apply + LeakyReLU, in place on d_out ----------------
__global__ __launch_bounds__(256) void bnapply_kernel(float* __restrict__ y,
                                                      const float* __restrict__ scale,
                                                      const float* __restrict__ shift) {
  const int total4 = BB * CC * HWSZ / 4;
  for (int e = blockIdx.x * 256 + threadIdx.x; e < total4; e += gridDim.x * 256) {
    float4 t = ((const float4*)y)[e];
    int oc = (e / (HWSZ / 4)) % CC;
    float sc = scale[oc], sh = shift[oc];
    float u;
    u = t.x * sc + sh; t.x = u >= 0.f ? u : 0.2f * u;
    u = t.y * sc + sh; t.y = u >= 0.f ? u : 0.2f * u;
    u = t.z * sc + sh; t.z = u >= 0.f ? u : 0.2f * u;
    u = t.w * sc + sh; t.w = u >= 0.f ? u : 0.2f * u;
    ((float4*)y)[e] = t;
  }
}

extern "C" void kernel_launch(void* const* d_in, const int* in_sizes, int n_in,
                              void* d_out, int out_size, void* d_ws, size_t ws_size,
                              hipStream_t stream) {
  const float* x     = (const float*)d_in[0];
  const float* wq    = (const float*)d_in[1];
  const float* bq    = (const float*)d_in[2];
  const float* wk    = (const float*)d_in[3];
  const float* bk    = (const float*)d_in[4];
  const float* wv    = (const float*)d_in[5];
  const float* bv    = (const float*)d_in[6];
  const float* w_out = (const float*)d_in[7];
  const float* b_out = (const float*)d_in[8];
  const float* gamma = (const float*)d_in[9];
  const float* beta  = (const float*)d_in[10];

  char* ws = (char*)d_ws;
  const size_t TB = (size_t)BB * CC * HWSZ * sizeof(bf16);   // 56,623,104 B per tensor
  bf16* q    = (bf16*)(ws);
  bf16* k    = (bf16*)(ws + TB);
  bf16* v    = (bf16*)(ws + 2 * TB);
  bf16* attn = (bf16*)(ws + 3 * TB);
  float* wT     = (float*)(ws + 4 * TB);                      // 1,327,104 B
  float* scores = (float*)(ws + 4 * TB + 1327104);            // 49,152 B
  float* bnsum  = (float*)(ws + 4 * TB + 1327104 + 49152);    // 768 B
  float* bnsqs  = bnsum + CC;                                 // 768 B
  float* probs  = bnsqs + CC;                                 // 49,152 B
  float* scale  = probs + 3 * BB * 256;
  float* shift  = scale + CC;
  float* y = (float*)d_out;

  // zero score accumulators + BN partial sums (contiguous region)
  hipMemsetAsync(scores, 0, 49152 + 2 * CC * 4, stream);

  prep_wT_kernel<<<(CC * CC * 9 + 255) / 256, 256, 0, stream>>>(w_out, wT);
  qkv_kernel<<<BB * 144, 256, 0, stream>>>(x, wq, bq, wk, bk, wv, bv, q, k, v);

  scores_kernel<2, 2, 48, 48, 0><<<BB * 16, 256, 0, stream>>>(q, k, scores);
  scores_kernel<3, 3, 32, 32, 1><<<BB * 16, 256, 0, stream>>>(q, k, scores);
  scores_kernel<4, 4, 24, 24, 2><<<BB * 16, 256, 0, stream>>>(q, k, scores);

  softmax_kernel<<<1, 512, 0, stream>>>(scores, probs);

  pv_kernel<2, 2, 48, 48, 0><<<BB * DKC, 256, 0, stream>>>(v, probs, attn);
  pv_kernel<3, 3, 32, 32, 1><<<BB * DKC, 256, 0, stream>>>(v, probs, attn);
  pv_kernel<4, 4, 24, 24, 2><<<BB * DKC, 256, 0, stream>>>(v, probs, attn);

  conv_kernel<<<3 * HH * BB, 256, 0, stream>>>(attn, wT, b_out, y, bnsum, bnsqs);

  bnfin_kernel<<<1, 256, 0, stream>>>(bnsum, bnsqs, gamma, beta, scale, shift);
  bnapply_kernel<<<2048, 256, 0, stream>>>(y, scale, shift);
}

// Round 2
// 2362.483 us; speedup vs baseline: 2.4323x; 2.4323x over previous
//
#include <hip/hip_runtime.h>
#include <hip/hip_bf16.h>

#define BB 16
#define CC 192
#define HH 96
#define WWW 96
#define HWSZ 9216
#define DKC 64

typedef __hip_bfloat16 bf16;
typedef __attribute__((ext_vector_type(8))) short s8v;
typedef __attribute__((ext_vector_type(4))) float f32x4;

__device__ __forceinline__ float bf2f(unsigned short u) {
  union { unsigned int i; float f; } x; x.i = ((unsigned int)u) << 16; return x.f;
}
__device__ __forceinline__ unsigned short f2bf(float f) {
  union { __hip_bfloat16 h; unsigned short u; } c; c.h = __float2bfloat16(f); return c.u;
}

// ---------------- prep: w_out [oc][c][ky][kx] -> wb9T [sh][oc][c] bf16 ----------------
__global__ __launch_bounds__(256) void prep_w_kernel(const float* __restrict__ w_out,
                                                     unsigned short* __restrict__ wb9T) {
  int e = blockIdx.x * 256 + threadIdx.x;
  if (e >= 9 * CC * CC) return;
  int c = e % CC;
  int oc = (e / CC) % CC;
  int sh = e / (CC * CC);
  wb9T[e] = f2bf(w_out[((size_t)(oc * CC + c)) * 9 + sh]);
}

// ---------------- QKV projection: q,k NCHW bf16; v NHWC bf16 ----------------
__global__ __launch_bounds__(256) void qkv_kernel(
    const float* __restrict__ x,
    const float* __restrict__ wq, const float* __restrict__ bq,
    const float* __restrict__ wk, const float* __restrict__ bk,
    const float* __restrict__ wv, const float* __restrict__ bv,
    bf16* __restrict__ q, bf16* __restrict__ k, unsigned short* __restrict__ v) {
  __shared__ float xt[CC][64];
  int b = blockIdx.x / 144;
  int tile = blockIdx.x % 144;
  int pix0 = tile * 64;
  const float* xb = x + (size_t)b * CC * HWSZ + pix0;
  for (int e = threadIdx.x; e < CC * 16; e += 256) {
    int c = e >> 4, seg = e & 15;
    float4 t4 = *(const float4*)(xb + (size_t)c * HWSZ + seg * 4);
    xt[c][seg * 4 + 0] = t4.x; xt[c][seg * 4 + 1] = t4.y;
    xt[c][seg * 4 + 2] = t4.z; xt[c][seg * 4 + 3] = t4.w;
  }
  __syncthreads();
  int lane = threadIdx.x & 63;
  int wid = threadIdx.x >> 6;
  for (int rb = 0; rb < 144; rb += 4) {
    int ro = wid * 144 + rb;
    int tsel = ro / CC, oc = ro % CC;
    const float* Wt = (tsel == 0 ? wq : tsel == 1 ? wk : wv) + (size_t)oc * CC;
    const float* Bt = (tsel == 0 ? bq : tsel == 1 ? bk : bv) + oc;
    float a0 = 0.f, a1 = 0.f, a2 = 0.f, a3 = 0.f;
    for (int c = 0; c < CC; c += 4) {
      float x0 = xt[c][lane], x1 = xt[c + 1][lane], x2 = xt[c + 2][lane], x3 = xt[c + 3][lane];
      float4 w0 = *(const float4*)(Wt + c);
      float4 w1 = *(const float4*)(Wt + CC + c);
      float4 w2 = *(const float4*)(Wt + 2 * CC + c);
      float4 w3 = *(const float4*)(Wt + 3 * CC + c);
      a0 += x0 * w0.x + x1 * w0.y + x2 * w0.z + x3 * w0.w;
      a1 += x0 * w1.x + x1 * w1.y + x2 * w1.z + x3 * w1.w;
      a2 += x0 * w2.x + x1 * w2.y + x2 * w2.z + x3 * w2.w;
      a3 += x0 * w3.x + x1 * w3.y + x2 * w3.z + x3 * w3.w;
    }
    if (tsel == 2) {
      unsigned short* Vt = v + ((size_t)(b * HWSZ + pix0 + lane)) * CC + oc;
      uint2 pk;
      pk.x = (unsigned int)f2bf(a0 + Bt[0]) | ((unsigned int)f2bf(a1 + Bt[1]) << 16);
      pk.y = (unsigned int)f2bf(a2 + Bt[2]) | ((unsigned int)f2bf(a3 + Bt[3]) << 16);
      *(uint2*)Vt = pk;
    } else {
      bf16* Ot = (tsel == 0 ? q : k) + ((size_t)b * CC + oc) * HWSZ + pix0 + lane;
      Ot[0]                = __float2bfloat16(a0 + Bt[0]);
      Ot[(size_t)HWSZ]     = __float2bfloat16(a1 + Bt[1]);
      Ot[(size_t)2 * HWSZ] = __float2bfloat16(a2 + Bt[2]);
      Ot[(size_t)3 * HWSZ] = __float2bfloat16(a3 + Bt[3]);
    }
  }
}

// ---------------- scores: P x P dots over D ----------------
template <int HS, int WS, int OH, int OW, int IDX>
__global__ __launch_bounds__(256) void scores_kernel(
    const bf16* __restrict__ q, const bf16* __restrict__ k, float* __restrict__ scores) {
  constexpr int P = HS * WS;
  constexpr int PAIRS = P * P;
  constexpr int NPOS = DKC * OH * OW;
  constexpr int NB = 16;
  constexpr int NSUB = (256 / PAIRS) < 1 ? 1 : (256 / PAIRS);
  __shared__ float qt[128][P];
  __shared__ float kt[128][P];
  int b = blockIdx.x / NB;
  int blk = blockIdx.x % NB;
  const bf16* qb = q + ((size_t)b * CC + IDX * DKC) * HWSZ;
  const bf16* kb = k + ((size_t)b * CC + IDX * DKC) * HWSZ;
  int pr = threadIdx.x % PAIRS;
  int sub = threadIdx.x / PAIRS;
  int pi = pr / P, qi = pr % P;
  float acc = 0.f;
  for (int pos0 = blk * 128; pos0 < NPOS; pos0 += NB * 128) {
    for (int e = threadIdx.x; e < 128 * P; e += 256) {
      int pos = e / P, pp = e % P;
      int posg = pos0 + pos;
      int cl = posg / (OH * OW);
      int rem = posg % (OH * OW);
      int r = rem / OW, s = rem % OW;
      int i = pp / WS, j = pp % WS;
      int off = cl * HWSZ + (r * HS + i) * WWW + s * WS + j;
      qt[pos][pp] = __bfloat162float(qb[off]);
      kt[pos][pp] = __bfloat162float(kb[off]);
    }
    __syncthreads();
    if (sub < NSUB) {
      for (int pos = sub; pos < 128; pos += NSUB)
        acc += qt[pos][pi] * kt[pos][qi];
    }
    __syncthreads();
  }
  if (sub < NSUB) atomicAdd(scores + ((IDX * BB + b) * 256 + pr), acc);
}

// ---------------- softmax over P ----------------
__global__ void softmax_kernel(const float* __restrict__ scores, float* __restrict__ probs) {
  int t = threadIdx.x;
  int idx, b, p, P; float scale;
  if (t < 64)       { idx = 0; b = t >> 2;           p = t & 3;         P = 4;  scale = 1.f / 384.f; }
  else if (t < 208) { int u = t - 64;  idx = 1; b = u / 9;  p = u % 9;  P = 9;  scale = 1.f / 256.f; }
  else if (t < 464) { int u = t - 208; idx = 2; b = u >> 4; p = u & 15; P = 16; scale = 1.f / 192.f; }
  else return;
  const float* row = scores + (idx * BB + b) * 256 + p * P;
  float* orow = probs + (idx * BB + b) * 256 + p * P;
  float vals[16];
  float m = -1e30f;
  for (int i = 0; i < P; i++) { vals[i] = row[i] * scale; m = fmaxf(m, vals[i]); }
  float s = 0.f;
  for (int i = 0; i < P; i++) { vals[i] = expf(vals[i] - m); s += vals[i]; }
  float inv = 1.f / s;
  for (int i = 0; i < P; i++) orow[i] = vals[i] * inv;
}

// ---------------- PV + unstitch: block = (b, r); writes attn NHWC ----------------
// v rows {r*HS+iq} feed output rows {i*OH+r} for all i -> each v row read once.
template <int HS, int WS, int OH, int OW, int IDX>
__global__ __launch_bounds__(256) void pv_kernel(
    const unsigned short* __restrict__ v, const float* __restrict__ probs,
    unsigned short* __restrict__ attn) {
  constexpr int P = HS * WS;
  __shared__ unsigned short vl[HS * 96 * 72];  // [iq][col][c(64)+pad8]
  __shared__ float pl[P * P];
  int b = blockIdx.x / OH;
  int r = blockIdx.x % OH;
  const int tid = threadIdx.x;
  for (int u = tid; u < HS * 96 * 8; u += 256) {
    int iq = u / 768, w = (u >> 3) % 96, cg = u & 7;
    *(uint4*)(vl + (iq * 96 + w) * 72 + cg * 8) =
        *(const uint4*)(v + ((size_t)(b * HWSZ + (r * HS + iq) * WWW + w)) * CC + IDX * 64 + cg * 8);
  }
  if (tid < P * P) pl[tid] = probs[(IDX * BB + b) * 256 + tid];
  __syncthreads();
  for (int u = tid; u < HS * 96 * 8; u += 256) {
    int i = u / 768, w = (u >> 3) % 96, cg = u & 7;
    int j = w / OW, s = w - j * OW;
    int p = i * WS + j;
    float acc[8];
    #pragma unroll
    for (int m = 0; m < 8; ++m) acc[m] = 0.f;
    #pragma unroll
    for (int iq = 0; iq < HS; ++iq) {
      #pragma unroll
      for (int jq = 0; jq < WS; ++jq) {
        float pw = pl[p * P + iq * WS + jq];
        s8v vv = *(const s8v*)(vl + (iq * 96 + s * WS + jq) * 72 + cg * 8);
        #pragma unroll
        for (int m = 0; m < 8; ++m) acc[m] += pw * bf2f((unsigned short)vv[m]);
      }
    }
    uint4 ov;
    ov.x = (unsigned int)f2bf(acc[0]) | ((unsigned int)f2bf(acc[1]) << 16);
    ov.y = (unsigned int)f2bf(acc[2]) | ((unsigned int)f2bf(acc[3]) << 16);
    ov.z = (unsigned int)f2bf(acc[4]) | ((unsigned int)f2bf(acc[5]) << 16);
    ov.w = (unsigned int)f2bf(acc[6]) | ((unsigned int)f2bf(acc[7]) << 16);
    *(uint4*)(attn + ((size_t)(b * HWSZ + (i * OH + r) * WWW + w)) * CC + IDX * 64 + cg * 8) = ov;
  }
}

// ---------------- conv3x3 via MFMA implicit GEMM + bias + BN partials ----------------
// Block: one output row (b,h). M=96 pixels, N=192 oc, K=192c x 9 shifts (54 x K32 steps).
__global__ __launch_bounds__(256) void conv_mfma_kernel(
    const unsigned short* __restrict__ attn, const unsigned short* __restrict__ wb9T,
    const float* __restrict__ b_out, float* __restrict__ y,
    float* __restrict__ bnsum, float* __restrict__ bnsqs) {
  __shared__ unsigned short al[2][3 * 98 * 32];  // [ky][w+halo][c32]
  __shared__ unsigned short bl[2][192 * 32];     // [oc][c32]
  const int tid = threadIdx.x;
  const int h = blockIdx.x % HH;
  const int b = blockIdx.x / HH;
  const int lane = tid & 63, wid = tid >> 6;
  const int lr = lane & 15, hi8 = (lane >> 4) * 8, rowb = (lane >> 4) * 4;
  const int n0 = wid * 48;

  f32x4 acc[6][3];
  #pragma unroll
  for (int mt = 0; mt < 6; ++mt)
    #pragma unroll
    for (int nt = 0; nt < 3; ++nt) acc[mt][nt] = (f32x4){0.f, 0.f, 0.f, 0.f};

  auto stageB = [&](int it2) {
    int chunk = it2 / 9, sh = it2 % 9;
    const unsigned short* src0 = wb9T + (size_t)sh * CC * CC + chunk * 32;
    unsigned short* dst = bl[it2 & 1];
    #pragma unroll
    for (int i = 0; i < 3; ++i) {
      int elem = tid * 8 + i * 2048;
      int oc = elem >> 5, cl = elem & 31;
      *(uint4*)(dst + elem) = *(const uint4*)(src0 + oc * CC + cl);
    }
  };
  auto stageA = [&](int chunk) {
    int c0 = chunk * 32;
    unsigned short* dst = al[chunk & 1];
    #pragma unroll
    for (int i = 0; i < 5; ++i) {
      int u = tid + i * 256;
      if (u < 1176) {
        int row = u / 392, rem = u % 392, wx = rem >> 2, qq = rem & 3;
        int hr = h + row - 1, w = wx - 1;
        uint4 val = make_uint4(0u, 0u, 0u, 0u);
        if (hr >= 0 && hr < HH && w >= 0 && w < WWW)
          val = *(const uint4*)(attn + ((size_t)(b * HWSZ + hr * WWW + w)) * CC + c0 + qq * 8);
        *(uint4*)(dst + (row * 98 + wx) * 32 + qq * 8) = val;
      }
    }
  };

  stageA(0);
  stageB(0);
  __syncthreads();
  for (int it = 0; it < 54; ++it) {
    int nxt = it + 1;
    if (nxt < 54) {
      stageB(nxt);
      if (nxt % 9 == 0) stageA(nxt / 9);
    }
    int chunk = it / 9, sh = it % 9, ky = sh / 3, kx = sh % 3;
    const unsigned short* A = al[chunk & 1];
    const unsigned short* Bl = bl[it & 1];
    s8v bf[3];
    #pragma unroll
    for (int nt = 0; nt < 3; ++nt)
      bf[nt] = *(const s8v*)(Bl + (n0 + nt * 16 + lr) * 32 + hi8);
    #pragma unroll
    for (int mt = 0; mt < 6; ++mt) {
      s8v a = *(const s8v*)(A + (ky * 98 + mt * 16 + lr + kx) * 32 + hi8);
      #pragma unroll
      for (int nt = 0; nt < 3; ++nt)
        acc[mt][nt] = __builtin_amdgcn_mfma_f32_16x16x32_bf16(a, bf[nt], acc[mt][nt], 0, 0, 0);
    }
    __syncthreads();
  }

  // epilogue: bias, store y NCHW, BN partial sums
  float s1[3], s2[3];
  #pragma unroll
  for (int nt = 0; nt < 3; ++nt) { s1[nt] = 0.f; s2[nt] = 0.f; }
  #pragma unroll
  for (int nt = 0; nt < 3; ++nt) {
    int oc = n0 + nt * 16 + lr;
    float bias = b_out[oc];
    #pragma unroll
    for (int mt = 0; mt < 6; ++mt) {
      float v0 = acc[mt][nt][0] + bias;
      float v1 = acc[mt][nt][1] + bias;
      float v2 = acc[mt][nt][2] + bias;
      float v3 = acc[mt][nt][3] + bias;
      s1[nt] += v0 + v1 + v2 + v3;
      s2[nt] += v0 * v0 + v1 * v1 + v2 * v2 + v3 * v3;
      float* yp = y + ((size_t)(b * CC + oc)) * HWSZ + h * WWW + mt * 16 + rowb;
      *(float4*)yp = make_float4(v0, v1, v2, v3);
    }
  }
  #pragma unroll
  for (int nt = 0; nt < 3; ++nt) {
    s1[nt] += __shfl_down(s1[nt], 32);
    s1[nt] += __shfl_down(s1[nt], 16);
    s2[nt] += __shfl_down(s2[nt], 32);
    s2[nt] += __shfl_down(s2[nt], 16);
  }
  if (lane < 16) {
    #pragma unroll
    for (int nt = 0; nt < 3; ++nt) {
      atomicAdd(bnsum + n0 + nt * 16 + lane, s1[nt]);
      atomicAdd(bnsqs + n0 + nt * 16 + lane, s2[nt]);
    }
  }
}

// ---------------- BN finalize ----------------
__global__ void bnfin_kernel(const float* __restrict__ bnsum, const float* __restrict__ bnsqs,
                             const float* __restrict__ gamma, const float* __restrict__ beta,
                             float* __restrict__ scale, float* __restrict__ shift) {
  int c = threadIdx.x;
  if (c >= CC) return;
  const float n = 16.f * 9216.f;
  float mean = bnsum[c] / n;
  float var = bnsqs[c] / n - mean * mean;
  float inv = rsqrtf(var + 1e-5f);
  float sc = gamma[c] * inv;
  scale[c] = sc;
  shift[c] = beta[c] - mean * sc;
}

// ---------------- BN apply + LeakyReLU, in place on d_out ----------------
__global__ __launch_bounds__(256) void bnapply_kernel(float* __restrict__ y,
                                                      const float* __restrict__ scale,
                                                      const float* __restrict__ shift) {
  const int total4 = BB * CC * HWSZ / 4;
  for (int e = blockIdx.x * 256 + threadIdx.x; e < total4; e += gridDim.x * 256) {
    float4 t = ((const float4*)y)[e];
    int oc = (e / (HWSZ / 4)) % CC;
    float sc = scale[oc], sh = shift[oc];
    float u;
    u = t.x * sc + sh; t.x = u >= 0.f ? u : 0.2f * u;
    u = t.y * sc + sh; t.y = u >= 0.f ? u : 0.2f * u;
    u = t.z * sc + sh; t.z = u >= 0.f ? u : 0.2f * u;
    u = t.w * sc + sh; t.w = u >= 0.f ? u : 0.2f * u;
    ((float4*)y)[e] = t;
  }
}

extern "C" void kernel_launch(void* const* d_in, const int* in_sizes, int n_in,
                              void* d_out, int out_size, void* d_ws, size_t ws_size,
                              hipStream_t stream) {
  const float* x     = (const float*)d_in[0];
  const float* wq    = (const float*)d_in[1];
  const float* bq    = (const float*)d_in[2];
  const float* wk    = (const float*)d_in[3];
  const float* bk    = (const float*)d_in[4];
  const float* wv    = (const float*)d_in[5];
  const float* bv    = (const float*)d_in[6];
  const float* w_out = (const float*)d_in[7];
  const float* b_out = (const float*)d_in[8];
  const float* gamma = (const float*)d_in[9];
  const float* beta  = (const float*)d_in[10];

  char* ws = (char*)d_ws;
  const size_t TB = (size_t)BB * CC * HWSZ * sizeof(bf16);   // 56,623,104 B per tensor
  bf16* q             = (bf16*)(ws);                          // NCHW
  bf16* k             = (bf16*)(ws + TB);                     // NCHW
  unsigned short* v   = (unsigned short*)(ws + 2 * TB);       // NHWC
  unsigned short* attn= (unsigned short*)(ws + 3 * TB);       // NHWC
  unsigned short* wb9T= (unsigned short*)(ws + 4 * TB);       // [9][192][192] bf16, 663,552 B
  float* scores = (float*)(ws + 4 * TB + 663552);             // 49,152 B
  float* bnsum  = scores + 3 * BB * 256;                      // 768 B
  float* bnsqs  = bnsum + CC;                                 // 768 B
  float* probs  = bnsqs + CC;                                 // 49,152 B
  float* scale  = probs + 3 * BB * 256;
  float* shift  = scale + CC;
  float* y = (float*)d_out;

  // zero scores + bn partials (contiguous)
  hipMemsetAsync(scores, 0, 49152 + 2 * CC * 4, stream);

  prep_w_kernel<<<(9 * CC * CC + 255) / 256, 256, 0, stream>>>(w_out, wb9T);
  qkv_kernel<<<BB * 144, 256, 0, stream>>>(x, wq, bq, wk, bk, wv, bv, q, k, v);

  scores_kernel<2, 2, 48, 48, 0><<<BB * 16, 256, 0, stream>>>(q, k, scores);
  scores_kernel<3, 3, 32, 32, 1><<<BB * 16, 256, 0, stream>>>(q, k, scores);
  scores_kernel<4, 4, 24, 24, 2><<<BB * 16, 256, 0, stream>>>(q, k, scores);

  softmax_kernel<<<1, 512, 0, stream>>>(scores, probs);

  pv_kernel<2, 2, 48, 48, 0><<<BB * 48, 256, 0, stream>>>(v, probs, attn);
  pv_kernel<3, 3, 32, 32, 1><<<BB * 32, 256, 0, stream>>>(v, probs, attn);
  pv_kernel<4, 4, 24, 24, 2><<<BB * 24, 256, 0, stream>>>(v, probs, attn);

  conv_mfma_kernel<<<BB * HH, 256, 0, stream>>>(attn, wb9T, b_out, y, bnsum, bnsqs);

  bnfin_kernel<<<1, 256, 0, stream>>>(bnsum, bnsqs, gamma, beta, scale, shift);
  bnapply_kernel<<<2048, 256, 0, stream>>>(y, scale, shift);
}

// Round 5
// 579.196 us; speedup vs baseline: 9.9211x; 4.0789x over previous
//
#include <hip/hip_runtime.h>
#include <hip/hip_bf16.h>

#define BB 16
#define CC 192
#define HH 96
#define WWW 96
#define HWSZ 9216
#define DKC 64

typedef __hip_bfloat16 bf16;
typedef __attribute__((ext_vector_type(8))) short s8v;
typedef __attribute__((ext_vector_type(4))) float f32x4;

__device__ __forceinline__ float bf2f(unsigned short u) {
  union { unsigned int i; float f; } x; x.i = ((unsigned int)u) << 16; return x.f;
}
__device__ __forceinline__ unsigned short f2bf(float f) {
  union { __hip_bfloat16 h; unsigned short u; } c; c.h = __float2bfloat16(f); return c.u;
}

// ---------------- prep: w_out [oc][c][ky][kx] -> wb9T [sh][oc][c] bf16 ----------------
__global__ __launch_bounds__(256) void prep_w_kernel(const float* __restrict__ w_out,
                                                     unsigned short* __restrict__ wb9T) {
  int e = blockIdx.x * 256 + threadIdx.x;
  if (e >= 9 * CC * CC) return;
  int c = e % CC;
  int oc = (e / CC) % CC;
  int sh = e / (CC * CC);
  wb9T[e] = f2bf(w_out[((size_t)(oc * CC + c)) * 9 + sh]);
}

// ---------------- prep: wq/wk/wv fp32 -> wqkv [sel][oc][c] bf16 ----------------
__global__ __launch_bounds__(256) void prep_wqkv_kernel(
    const float* __restrict__ wq, const float* __restrict__ wk, const float* __restrict__ wv,
    unsigned short* __restrict__ wqkv) {
  int e = blockIdx.x * 256 + threadIdx.x;
  if (e >= 3 * CC * CC) return;
  int sel = e / (CC * CC), r = e % (CC * CC);
  const float* w = sel == 0 ? wq : sel == 1 ? wk : wv;
  wqkv[e] = f2bf(w[r]);
}

// ---------------- x: NCHW fp32 -> NHWC bf16 ----------------
__global__ __launch_bounds__(256) void xcvt_kernel(const float* __restrict__ x,
                                                   unsigned short* __restrict__ xb) {
  __shared__ float xt[CC][65];
  int b = blockIdx.x / 144, tile = blockIdx.x % 144;
  int pix0 = tile * 64;
  const float* xsrc = x + (size_t)b * CC * HWSZ + pix0;
  for (int e = threadIdx.x; e < CC * 16; e += 256) {
    int c = e >> 4, seg = e & 15;
    float4 t4 = *(const float4*)(xsrc + (size_t)c * HWSZ + seg * 4);
    xt[c][seg * 4 + 0] = t4.x; xt[c][seg * 4 + 1] = t4.y;
    xt[c][seg * 4 + 2] = t4.z; xt[c][seg * 4 + 3] = t4.w;
  }
  __syncthreads();
  unsigned short* dst = xb + ((size_t)(b * HWSZ + pix0)) * CC;
  for (int e = threadIdx.x; e < 24 * 64; e += 256) {
    int cg = e >> 6, p = e & 63;
    uint4 ov;
    unsigned short* ou = (unsigned short*)&ov;
    #pragma unroll
    for (int j = 0; j < 8; ++j) ou[j] = f2bf(xt[cg * 8 + j][p]);
    *(uint4*)(dst + (size_t)p * CC + cg * 8) = ov;
  }
}

// ---------------- QKV via MFMA: block = (b, h, sel); writes q/k/v NHWC bf16 ----------------
// Single-buffered staging; staging loops cover the FULL tile:
//   A: 96 pix x 32 ch = 384 uint4;  B: 192 oc x 32 ch = 768 uint4 (= 3 x 256 threads).
__global__ __launch_bounds__(256) void qkv_mfma_kernel(
    const unsigned short* __restrict__ xb, const unsigned short* __restrict__ wqkv,
    const float* __restrict__ bq, const float* __restrict__ bk, const float* __restrict__ bv,
    unsigned short* __restrict__ q, unsigned short* __restrict__ k,
    unsigned short* __restrict__ v) {
  __shared__ unsigned short al[96 * 32];    // [pix][c32]
  __shared__ unsigned short bl[192 * 32];   // [oc][c32]
  __shared__ unsigned short vt[96 * 224];   // transpose buffer (separate)
  const int tid = threadIdx.x;
  const int sel = blockIdx.x % 3;
  const int h = (blockIdx.x / 3) % HH;
  const int b = blockIdx.x / (3 * HH);
  const int lane = tid & 63, wid = tid >> 6;
  const int lr = lane & 15, hi8 = (lane >> 4) * 8, rowb = (lane >> 4) * 4;
  const int n0 = wid * 48;
  const unsigned short* xrow = xb + ((size_t)(b * HWSZ + h * WWW)) * CC;
  const unsigned short* wsel = wqkv + (size_t)sel * CC * CC;

  f32x4 acc[6][3];
  #pragma unroll
  for (int mt = 0; mt < 6; ++mt)
    #pragma unroll
    for (int nt = 0; nt < 3; ++nt) acc[mt][nt] = (f32x4){0.f, 0.f, 0.f, 0.f};

  for (int ck = 0; ck < 6; ++ck) {
    // stage A: 96 pixels x 32 ch (full coverage: 384 uint4)
    #pragma unroll
    for (int i = 0; i < 2; ++i) {
      int u = tid + i * 256;
      if (u < 384) {
        int pix = u >> 2, qq = u & 3;
        *(uint4*)(al + pix * 32 + qq * 8) =
            *(const uint4*)(xrow + (size_t)pix * CC + ck * 32 + qq * 8);
      }
    }
    // stage B: 192 oc x 32 ch (full coverage: 768 uint4 = 3*256)
    #pragma unroll
    for (int i = 0; i < 3; ++i) {
      int u = tid + i * 256;
      int oc = u >> 2, qq = u & 3;
      *(uint4*)(bl + oc * 32 + qq * 8) =
          *(const uint4*)(wsel + oc * CC + ck * 32 + qq * 8);
    }
    __syncthreads();
    s8v bfr[3];
    #pragma unroll
    for (int nt = 0; nt < 3; ++nt)
      bfr[nt] = *(const s8v*)(bl + (n0 + nt * 16 + lr) * 32 + hi8);
    #pragma unroll
    for (int mt = 0; mt < 6; ++mt) {
      s8v a = *(const s8v*)(al + (mt * 16 + lr) * 32 + hi8);
      #pragma unroll
      for (int nt = 0; nt < 3; ++nt)
        acc[mt][nt] = __builtin_amdgcn_mfma_f32_16x16x32_bf16(a, bfr[nt], acc[mt][nt], 0, 0, 0);
    }
    __syncthreads();
  }

  // epilogue: bias, LDS transpose, NHWC store
  const float* bsel = (sel == 0 ? bq : sel == 1 ? bk : bv);
  float bias[3];
  #pragma unroll
  for (int nt = 0; nt < 3; ++nt) bias[nt] = bsel[n0 + nt * 16 + lr];
  #pragma unroll
  for (int mt = 0; mt < 6; ++mt)
    #pragma unroll
    for (int nt = 0; nt < 3; ++nt)
      #pragma unroll
      for (int i = 0; i < 4; ++i)
        vt[(mt * 16 + rowb + i) * 224 + n0 + nt * 16 + lr] = f2bf(acc[mt][nt][i] + bias[nt]);
  __syncthreads();
  unsigned short* dst = (sel == 0 ? q : sel == 1 ? k : v) + ((size_t)(b * HWSZ + h * WWW)) * CC;
  for (int e = tid; e < 96 * 24; e += 256) {
    int p = e % 96, cg = e / 96;
    *(uint4*)(dst + (size_t)p * CC + cg * 8) = *(uint4*)(vt + p * 224 + cg * 8);
  }
}

// ---------------- scores: P x P dots over D, NHWC q/k ----------------
template <int HS, int WS, int OH, int OW, int IDX>
__global__ __launch_bounds__(256) void scores_kernel(
    const unsigned short* __restrict__ q, const unsigned short* __restrict__ k,
    float* __restrict__ scores) {
  constexpr int P = HS * WS;
  constexpr int PAIRS = P * P;
  constexpr int NB = 16;
  constexpr int NSUB = (256 / PAIRS) < 1 ? 1 : (256 / PAIRS);
  __shared__ float qt[128][P + 1];
  __shared__ float kt[128][P + 1];
  int b = blockIdx.x / NB;
  int blk = blockIdx.x % NB;
  const unsigned short* qb = q + (size_t)b * HWSZ * CC;
  const unsigned short* kb = k + (size_t)b * HWSZ * CC;
  int pr = threadIdx.x % PAIRS;
  int sub = threadIdx.x / PAIRS;
  int pi = pr / P, qi = pr % P;
  float acc = 0.f;
  for (int rs0 = blk * 2; rs0 < OH * OW; rs0 += NB * 2) {
    if (threadIdx.x < 16 * P) {
      int cg = threadIdx.x & 7;
      int t2 = threadIdx.x >> 3;
      int pp = t2 % P, rs2 = t2 / P;
      int rs = rs0 + rs2;
      int r = rs / OW, s = rs % OW;
      int i = pp / WS, j = pp % WS;
      int pixel = (r * HS + i) * WWW + s * WS + j;
      uint4 qv = *(const uint4*)(qb + (size_t)pixel * CC + IDX * 64 + cg * 8);
      uint4 kv = *(const uint4*)(kb + (size_t)pixel * CC + IDX * 64 + cg * 8);
      const unsigned short* qu = (const unsigned short*)&qv;
      const unsigned short* ku = (const unsigned short*)&kv;
      #pragma unroll
      for (int m = 0; m < 8; ++m) {
        qt[rs2 * 64 + cg * 8 + m][pp] = bf2f(qu[m]);
        kt[rs2 * 64 + cg * 8 + m][pp] = bf2f(ku[m]);
      }
    }
    __syncthreads();
    if (sub < NSUB) {
      #pragma unroll 4
      for (int pos = sub; pos < 128; pos += NSUB)
        acc += qt[pos][pi] * kt[pos][qi];
    }
    __syncthreads();
  }
  if (sub < NSUB) atomicAdd(scores + ((IDX * BB + b) * 256 + pr), acc);
}

// ---------------- softmax over P ----------------
__global__ void softmax_kernel(const float* __restrict__ scores, float* __restrict__ probs) {
  int t = threadIdx.x;
  int idx, b, p, P; float scale;
  if (t < 64)       { idx = 0; b = t >> 2;           p = t & 3;         P = 4;  scale = 1.f / 384.f; }
  else if (t < 208) { int u = t - 64;  idx = 1; b = u / 9;  p = u % 9;  P = 9;  scale = 1.f / 256.f; }
  else if (t < 464) { int u = t - 208; idx = 2; b = u >> 4; p = u & 15; P = 16; scale = 1.f / 192.f; }
  else return;
  const float* row = scores + (idx * BB + b) * 256 + p * P;
  float* orow = probs + (idx * BB + b) * 256 + p * P;
  float vals[16];
  float m = -1e30f;
  for (int i = 0; i < P; i++) { vals[i] = row[i] * scale; m = fmaxf(m, vals[i]); }
  float s = 0.f;
  for (int i = 0; i < P; i++) { vals[i] = expf(vals[i] - m); s += vals[i]; }
  float inv = 1.f / s;
  for (int i = 0; i < P; i++) orow[i] = vals[i] * inv;
}

// ---------------- PV + unstitch: block = (b, r); v/attn NHWC ----------------
template <int HS, int WS, int OH, int OW, int IDX>
__global__ __launch_bounds__(256) void pv_kernel(
    const unsigned short* __restrict__ v, const float* __restrict__ probs,
    unsigned short* __restrict__ attn) {
  constexpr int P = HS * WS;
  __shared__ unsigned short vl[HS * 96 * 72];  // [iq][col][c(64)+pad8]
  __shared__ float pl[P * P];
  int b = blockIdx.x / OH;
  int r = blockIdx.x % OH;
  const int tid = threadIdx.x;
  for (int u = tid; u < HS * 96 * 8; u += 256) {
    int iq = u / 768, w = (u >> 3) % 96, cg = u & 7;
    *(uint4*)(vl + (iq * 96 + w) * 72 + cg * 8) =
        *(const uint4*)(v + ((size_t)(b * HWSZ + (r * HS + iq) * WWW + w)) * CC + IDX * 64 + cg * 8);
  }
  if (tid < P * P) pl[tid] = probs[(IDX * BB + b) * 256 + tid];
  __syncthreads();
  for (int u = tid; u < HS * 96 * 8; u += 256) {
    int i = u / 768, w = (u >> 3) % 96, cg = u & 7;
    int j = w / OW, s = w - j * OW;
    int p = i * WS + j;
    float acc[8];
    #pragma unroll
    for (int m = 0; m < 8; ++m) acc[m] = 0.f;
    #pragma unroll
    for (int iq = 0; iq < HS; ++iq) {
      #pragma unroll
      for (int jq = 0; jq < WS; ++jq) {
        float pw = pl[p * P + iq * WS + jq];
        s8v vv = *(const s8v*)(vl + (iq * 96 + s * WS + jq) * 72 + cg * 8);
        #pragma unroll
        for (int m = 0; m < 8; ++m) acc[m] += pw * bf2f((unsigned short)vv[m]);
      }
    }
    uint4 ov;
    ov.x = (unsigned int)f2bf(acc[0]) | ((unsigned int)f2bf(acc[1]) << 16);
    ov.y = (unsigned int)f2bf(acc[2]) | ((unsigned int)f2bf(acc[3]) << 16);
    ov.z = (unsigned int)f2bf(acc[4]) | ((unsigned int)f2bf(acc[5]) << 16);
    ov.w = (unsigned int)f2bf(acc[6]) | ((unsigned int)f2bf(acc[7]) << 16);
    *(uint4*)(attn + ((size_t)(b * HWSZ + (i * OH + r) * WWW + w)) * CC + IDX * 64 + cg * 8) = ov;
  }
}

// ---------------- conv3x3 via MFMA implicit GEMM + bias + BN partials ----------------
__global__ __launch_bounds__(256) void conv_mfma_kernel(
    const unsigned short* __restrict__ attn, const unsigned short* __restrict__ wb9T,
    const float* __restrict__ b_out, float* __restrict__ y,
    float* __restrict__ bnsum, float* __restrict__ bnsqs) {
  __shared__ unsigned short al[2][3 * 98 * 32];  // [ky][w+halo][c32]
  __shared__ unsigned short bl[2][192 * 32];     // [oc][c32]
  const int tid = threadIdx.x;
  const int h = blockIdx.x % HH;
  const int b = blockIdx.x / HH;
  const int lane = tid & 63, wid = tid >> 6;
  const int lr = lane & 15, hi8 = (lane >> 4) * 8, rowb = (lane >> 4) * 4;
  const int n0 = wid * 48;

  f32x4 acc[6][3];
  #pragma unroll
  for (int mt = 0; mt < 6; ++mt)
    #pragma unroll
    for (int nt = 0; nt < 3; ++nt) acc[mt][nt] = (f32x4){0.f, 0.f, 0.f, 0.f};

  auto stageB = [&](int it2) {
    int chunk = it2 / 9, sh = it2 % 9;
    const unsigned short* src0 = wb9T + (size_t)sh * CC * CC + chunk * 32;
    unsigned short* dst = bl[it2 & 1];
    #pragma unroll
    for (int i = 0; i < 3; ++i) {
      int elem = tid * 8 + i * 2048;
      int oc = elem >> 5, cl = elem & 31;
      *(uint4*)(dst + elem) = *(const uint4*)(src0 + oc * CC + cl);
    }
  };
  auto stageA = [&](int chunk) {
    int c0 = chunk * 32;
    unsigned short* dst = al[chunk & 1];
    #pragma unroll
    for (int i = 0; i < 5; ++i) {
      int u = tid + i * 256;
      if (u < 1176) {
        int row = u / 392, rem = u % 392, wx = rem >> 2, qq = rem & 3;
        int hr = h + row - 1, w = wx - 1;
        uint4 val = make_uint4(0u, 0u, 0u, 0u);
        if (hr >= 0 && hr < HH && w >= 0 && w < WWW)
          val = *(const uint4*)(attn + ((size_t)(b * HWSZ + hr * WWW + w)) * CC + c0 + qq * 8);
        *(uint4*)(dst + (row * 98 + wx) * 32 + qq * 8) = val;
      }
    }
  };

  stageA(0);
  stageB(0);
  __syncthreads();
  for (int it = 0; it < 54; ++it) {
    int nxt = it + 1;
    if (nxt < 54) {
      stageB(nxt);
      if (nxt % 9 == 0) stageA(nxt / 9);
    }
    int chunk = it / 9, sh = it % 9, ky = sh / 3, kx = sh % 3;
    const unsigned short* A = al[chunk & 1];
    const unsigned short* Bl = bl[it & 1];
    s8v bf[3];
    #pragma unroll
    for (int nt = 0; nt < 3; ++nt)
      bf[nt] = *(const s8v*)(Bl + (n0 + nt * 16 + lr) * 32 + hi8);
    #pragma unroll
    for (int mt = 0; mt < 6; ++mt) {
      s8v a = *(const s8v*)(A + (ky * 98 + mt * 16 + lr + kx) * 32 + hi8);
      #pragma unroll
      for (int nt = 0; nt < 3; ++nt)
        acc[mt][nt] = __builtin_amdgcn_mfma_f32_16x16x32_bf16(a, bf[nt], acc[mt][nt], 0, 0, 0);
    }
    __syncthreads();
  }

  float s1[3], s2[3];
  #pragma unroll
  for (int nt = 0; nt < 3; ++nt) { s1[nt] = 0.f; s2[nt] = 0.f; }
  #pragma unroll
  for (int nt = 0; nt < 3; ++nt) {
    int oc = n0 + nt * 16 + lr;
    float bias = b_out[oc];
    #pragma unroll
    for (int mt = 0; mt < 6; ++mt) {
      float v0 = acc[mt][nt][0] + bias;
      float v1 = acc[mt][nt][1] + bias;
      float v2 = acc[mt][nt][2] + bias;
      float v3 = acc[mt][nt][3] + bias;
      s1[nt] += v0 + v1 + v2 + v3;
      s2[nt] += v0 * v0 + v1 * v1 + v2 * v2 + v3 * v3;
      float* yp = y + ((size_t)(b * CC + oc)) * HWSZ + h * WWW + mt * 16 + rowb;
      *(float4*)yp = make_float4(v0, v1, v2, v3);
    }
  }
  #pragma unroll
  for (int nt = 0; nt < 3; ++nt) {
    s1[nt] += __shfl_down(s1[nt], 32);
    s1[nt] += __shfl_down(s1[nt], 16);
    s2[nt] += __shfl_down(s2[nt], 32);
    s2[nt] += __shfl_down(s2[nt], 16);
  }
  if (lane < 16) {
    #pragma unroll
    for (int nt = 0; nt < 3; ++nt) {
      atomicAdd(bnsum + n0 + nt * 16 + lane, s1[nt]);
      atomicAdd(bnsqs + n0 + nt * 16 + lane, s2[nt]);
    }
  }
}

// ---------------- BN finalize ----------------
__global__ void bnfin_kernel(const float* __restrict__ bnsum, const float* __restrict__ bnsqs,
                             const float* __restrict__ gamma, const float* __restrict__ beta,
                             float* __restrict__ scale, float* __restrict__ shift) {
  int c = threadIdx.x;
  if (c >= CC) return;
  const float n = 16.f * 9216.f;
  float mean = bnsum[c] / n;
  float var = bnsqs[c] / n - mean * mean;
  float inv = rsqrtf(var + 1e-5f);
  float sc = gamma[c] * inv;
  scale[c] = sc;
  shift[c] = beta[c] - mean * sc;
}

// ---------------- BN apply + LeakyReLU, in place on d_out ----------------
__global__ __launch_bounds__(256) void bnapply_kernel(float* __restrict__ y,
                                                      const float* __restrict__ scale,
                                                      const float* __restrict__ shift) {
  const int total4 = BB * CC * HWSZ / 4;
  for (int e = blockIdx.x * 256 + threadIdx.x; e < total4; e += gridDim.x * 256) {
    float4 t = ((const float4*)y)[e];
    int oc = (e / (HWSZ / 4)) % CC;
    float sc = scale[oc], sh = shift[oc];
    float u;
    u = t.x * sc + sh; t.x = u >= 0.f ? u : 0.2f * u;
    u = t.y * sc + sh; t.y = u >= 0.f ? u : 0.2f * u;
    u = t.z * sc + sh; t.z = u >= 0.f ? u : 0.2f * u;
    u = t.w * sc + sh; t.w = u >= 0.f ? u : 0.2f * u;
    ((float4*)y)[e] = t;
  }
}

extern "C" void kernel_launch(void* const* d_in, const int* in_sizes, int n_in,
                              void* d_out, int out_size, void* d_ws, size_t ws_size,
                              hipStream_t stream) {
  const float* x     = (const float*)d_in[0];
  const float* wq    = (const float*)d_in[1];
  const float* bq    = (const float*)d_in[2];
  const float* wk    = (const float*)d_in[3];
  const float* bk    = (const float*)d_in[4];
  const float* wv    = (const float*)d_in[5];
  const float* bv    = (const float*)d_in[6];
  const float* w_out = (const float*)d_in[7];
  const float* b_out = (const float*)d_in[8];
  const float* gamma = (const float*)d_in[9];
  const float* beta  = (const float*)d_in[10];

  char* ws = (char*)d_ws;
  const size_t TB = (size_t)BB * CC * HWSZ * sizeof(bf16);   // 56,623,104 B per tensor
  unsigned short* q    = (unsigned short*)(ws);               // NHWC bf16
  unsigned short* k    = (unsigned short*)(ws + TB);          // NHWC bf16
  unsigned short* v    = (unsigned short*)(ws + 2 * TB);      // NHWC bf16
  unsigned short* attn = (unsigned short*)(ws + 3 * TB);      // NHWC bf16; ALSO aliases xb
  unsigned short* xb   = attn;                                // x NHWC bf16 (dead before pv writes attn)
  unsigned short* wb9T = (unsigned short*)(ws + 4 * TB);      // [9][192][192] bf16
  unsigned short* wqkv = (unsigned short*)(ws + 4 * TB + 663552);  // [3][192][192] bf16
  float* scores = (float*)(ws + 4 * TB + 663552 + 221184);
  float* bnsum  = scores + 3 * BB * 256;
  float* bnsqs  = bnsum + CC;
  float* probs  = bnsqs + CC;
  float* scale  = probs + 3 * BB * 256;
  float* shift  = scale + CC;
  float* y = (float*)d_out;

  // zero scores + bn partials (contiguous)
  hipMemsetAsync(scores, 0, 49152 + 2 * CC * 4, stream);

  prep_w_kernel<<<(9 * CC * CC + 255) / 256, 256, 0, stream>>>(w_out, wb9T);
  prep_wqkv_kernel<<<(3 * CC * CC + 255) / 256, 256, 0, stream>>>(wq, wk, wv, wqkv);

  xcvt_kernel<<<BB * 144, 256, 0, stream>>>(x, xb);
  qkv_mfma_kernel<<<BB * HH * 3, 256, 0, stream>>>(xb, wqkv, bq, bk, bv, q, k, v);

  scores_kernel<2, 2, 48, 48, 0><<<BB * 16, 256, 0, stream>>>(q, k, scores);
  scores_kernel<3, 3, 32, 32, 1><<<BB * 16, 256, 0, stream>>>(q, k, scores);
  scores_kernel<4, 4, 24, 24, 2><<<BB * 16, 256, 0, stream>>>(q, k, scores);

  softmax_kernel<<<1, 512, 0, stream>>>(scores, probs);

  pv_kernel<2, 2, 48, 48, 0><<<BB * 48, 256, 0, stream>>>(v, probs, attn);
  pv_kernel<3, 3, 32, 32, 1><<<BB * 32, 256, 0, stream>>>(v, probs, attn);
  pv_kernel<4, 4, 24, 24, 2><<<BB * 24, 256, 0, stream>>>(v, probs, attn);

  conv_mfma_kernel<<<BB * HH, 256, 0, stream>>>(attn, wb9T, b_out, y, bnsum, bnsqs);

  bnfin_kernel<<<1, 256, 0, stream>>>(bnsum, bnsqs, gamma, beta, scale, shift);
  bnapply_kernel<<<2048, 256, 0, stream>>>(y, scale, shift);
}

// Round 6
// 551.908 us; speedup vs baseline: 10.4117x; 1.0494x over previous
//
#include <hip/hip_runtime.h>
#include <hip/hip_bf16.h>

#define BB 16
#define CC 192
#define HH 96
#define WWW 96
#define HWSZ 9216
#define DKC 64

typedef __hip_bfloat16 bf16;
typedef __attribute__((ext_vector_type(8))) short s8v;
typedef __attribute__((ext_vector_type(4))) float f32x4;

__device__ __forceinline__ float bf2f(unsigned short u) {
  union { unsigned int i; float f; } x; x.i = ((unsigned int)u) << 16; return x.f;
}
__device__ __forceinline__ unsigned short f2bf(float f) {
  union { __hip_bfloat16 h; unsigned short u; } c; c.h = __float2bfloat16(f); return c.u;
}

// ---------------- prep: w_out [oc][c][ky][kx] -> wb9T [sh][oc][c] bf16 ----------------
__global__ __launch_bounds__(256) void prep_w_kernel(const float* __restrict__ w_out,
                                                     unsigned short* __restrict__ wb9T) {
  int e = blockIdx.x * 256 + threadIdx.x;
  if (e >= 9 * CC * CC) return;
  int c = e % CC;
  int oc = (e / CC) % CC;
  int sh = e / (CC * CC);
  wb9T[e] = f2bf(w_out[((size_t)(oc * CC + c)) * 9 + sh]);
}

// ---------------- prep: wq/wk/wv fp32 -> wqkv [sel][oc][c] bf16 ----------------
__global__ __launch_bounds__(256) void prep_wqkv_kernel(
    const float* __restrict__ wq, const float* __restrict__ wk, const float* __restrict__ wv,
    unsigned short* __restrict__ wqkv) {
  int e = blockIdx.x * 256 + threadIdx.x;
  if (e >= 3 * CC * CC) return;
  int sel = e / (CC * CC), r = e % (CC * CC);
  const float* w = sel == 0 ? wq : sel == 1 ? wk : wv;
  wqkv[e] = f2bf(w[r]);
}

// ---------------- x: NCHW fp32 -> NHWC bf16 ----------------
__global__ __launch_bounds__(256) void xcvt_kernel(const float* __restrict__ x,
                                                   unsigned short* __restrict__ xb) {
  __shared__ float xt[CC][65];
  int b = blockIdx.x / 144, tile = blockIdx.x % 144;
  int pix0 = tile * 64;
  const float* xsrc = x + (size_t)b * CC * HWSZ + pix0;
  for (int e = threadIdx.x; e < CC * 16; e += 256) {
    int c = e >> 4, seg = e & 15;
    float4 t4 = *(const float4*)(xsrc + (size_t)c * HWSZ + seg * 4);
    xt[c][seg * 4 + 0] = t4.x; xt[c][seg * 4 + 1] = t4.y;
    xt[c][seg * 4 + 2] = t4.z; xt[c][seg * 4 + 3] = t4.w;
  }
  __syncthreads();
  unsigned short* dst = xb + ((size_t)(b * HWSZ + pix0)) * CC;
  for (int e = threadIdx.x; e < 24 * 64; e += 256) {
    int cg = e >> 6, p = e & 63;
    uint4 ov;
    unsigned short* ou = (unsigned short*)&ov;
    #pragma unroll
    for (int j = 0; j < 8; ++j) ou[j] = f2bf(xt[cg * 8 + j][p]);
    *(uint4*)(dst + (size_t)p * CC + cg * 8) = ov;
  }
}

// ---------------- QKV via MFMA: A in LDS (pad-40), B global->reg; 1 barrier/chunk ----------------
__global__ __launch_bounds__(256) void qkv_mfma_kernel(
    const unsigned short* __restrict__ xb, const unsigned short* __restrict__ wqkv,
    const float* __restrict__ bq, const float* __restrict__ bk, const float* __restrict__ bv,
    unsigned short* __restrict__ q, unsigned short* __restrict__ k,
    unsigned short* __restrict__ v) {
  __shared__ unsigned short al[2][96 * 40];   // [pix][c32 + pad8]
  __shared__ unsigned short vt[96 * 224];     // transpose buffer
  const int tid = threadIdx.x;
  const int sel = blockIdx.x % 3;
  const int h = (blockIdx.x / 3) % HH;
  const int b = blockIdx.x / (3 * HH);
  const int lane = tid & 63, wid = tid >> 6;
  const int lr = lane & 15, hi8 = (lane >> 4) * 8, rowb = (lane >> 4) * 4;
  const int n0 = wid * 48;
  const unsigned short* xrow = xb + ((size_t)(b * HWSZ + h * WWW)) * CC;
  const unsigned short* wsel = wqkv + (size_t)sel * CC * CC;

  f32x4 acc[6][3];
  #pragma unroll
  for (int mt = 0; mt < 6; ++mt)
    #pragma unroll
    for (int nt = 0; nt < 3; ++nt) acc[mt][nt] = (f32x4){0.f, 0.f, 0.f, 0.f};

  auto stageA = [&](int ck) {
    #pragma unroll
    for (int i = 0; i < 2; ++i) {
      int u = tid + i * 256;
      if (u < 384) {
        int pix = u >> 2, qq = u & 3;
        *(uint4*)(al[ck & 1] + pix * 40 + qq * 8) =
            *(const uint4*)(xrow + (size_t)pix * CC + ck * 32 + qq * 8);
      }
    }
  };
  auto loadB = [&](int ck, s8v* dst) {
    const unsigned short* src = wsel + ck * 32 + hi8;
    #pragma unroll
    for (int nt = 0; nt < 3; ++nt)
      dst[nt] = *(const s8v*)(src + (size_t)(n0 + nt * 16 + lr) * CC);
  };

  s8v bcur[3], bnxt[3];
  stageA(0);
  loadB(0, bcur);
  __syncthreads();
  for (int ck = 0; ck < 6; ++ck) {
    if (ck < 5) { stageA(ck + 1); loadB(ck + 1, bnxt); }
    const unsigned short* A = al[ck & 1];
    #pragma unroll
    for (int mt = 0; mt < 6; ++mt) {
      s8v a = *(const s8v*)(A + (mt * 16 + lr) * 40 + hi8);
      #pragma unroll
      for (int nt = 0; nt < 3; ++nt)
        acc[mt][nt] = __builtin_amdgcn_mfma_f32_16x16x32_bf16(a, bcur[nt], acc[mt][nt], 0, 0, 0);
    }
    #pragma unroll
    for (int nt = 0; nt < 3; ++nt) bcur[nt] = bnxt[nt];
    __syncthreads();
  }

  // epilogue: bias, LDS transpose, NHWC store
  const float* bsel = (sel == 0 ? bq : sel == 1 ? bk : bv);
  float bias[3];
  #pragma unroll
  for (int nt = 0; nt < 3; ++nt) bias[nt] = bsel[n0 + nt * 16 + lr];
  #pragma unroll
  for (int mt = 0; mt < 6; ++mt)
    #pragma unroll
    for (int nt = 0; nt < 3; ++nt)
      #pragma unroll
      for (int i = 0; i < 4; ++i)
        vt[(mt * 16 + rowb + i) * 224 + n0 + nt * 16 + lr] = f2bf(acc[mt][nt][i] + bias[nt]);
  __syncthreads();
  unsigned short* dst = (sel == 0 ? q : sel == 1 ? k : v) + ((size_t)(b * HWSZ + h * WWW)) * CC;
  for (int e = tid; e < 96 * 24; e += 256) {
    int p = e % 96, cg = e / 96;
    *(uint4*)(dst + (size_t)p * CC + cg * 8) = *(uint4*)(vt + p * 224 + cg * 8);
  }
}

// ---------------- scores: P x P dots over D, NHWC q/k ----------------
template <int HS, int WS, int OH, int OW, int IDX>
__global__ __launch_bounds__(256) void scores_kernel(
    const unsigned short* __restrict__ q, const unsigned short* __restrict__ k,
    float* __restrict__ scores) {
  constexpr int P = HS * WS;
  constexpr int PAIRS = P * P;
  constexpr int NB = 16;
  constexpr int NSUB = (256 / PAIRS) < 1 ? 1 : (256 / PAIRS);
  __shared__ float qt[128][P + 1];
  __shared__ float kt[128][P + 1];
  int b = blockIdx.x / NB;
  int blk = blockIdx.x % NB;
  const unsigned short* qb = q + (size_t)b * HWSZ * CC;
  const unsigned short* kb = k + (size_t)b * HWSZ * CC;
  int pr = threadIdx.x % PAIRS;
  int sub = threadIdx.x / PAIRS;
  int pi = pr / P, qi = pr % P;
  float acc = 0.f;
  for (int rs0 = blk * 2; rs0 < OH * OW; rs0 += NB * 2) {
    if (threadIdx.x < 16 * P) {
      int cg = threadIdx.x & 7;
      int t2 = threadIdx.x >> 3;
      int pp = t2 % P, rs2 = t2 / P;
      int rs = rs0 + rs2;
      int r = rs / OW, s = rs % OW;
      int i = pp / WS, j = pp % WS;
      int pixel = (r * HS + i) * WWW + s * WS + j;
      uint4 qv = *(const uint4*)(qb + (size_t)pixel * CC + IDX * 64 + cg * 8);
      uint4 kv = *(const uint4*)(kb + (size_t)pixel * CC + IDX * 64 + cg * 8);
      const unsigned short* qu = (const unsigned short*)&qv;
      const unsigned short* ku = (const unsigned short*)&kv;
      #pragma unroll
      for (int m = 0; m < 8; ++m) {
        qt[rs2 * 64 + cg * 8 + m][pp] = bf2f(qu[m]);
        kt[rs2 * 64 + cg * 8 + m][pp] = bf2f(ku[m]);
      }
    }
    __syncthreads();
    if (sub < NSUB) {
      #pragma unroll 4
      for (int pos = sub; pos < 128; pos += NSUB)
        acc += qt[pos][pi] * kt[pos][qi];
    }
    __syncthreads();
  }
  if (sub < NSUB) atomicAdd(scores + ((IDX * BB + b) * 256 + pr), acc);
}

// ---------------- softmax over P ----------------
__global__ void softmax_kernel(const float* __restrict__ scores, float* __restrict__ probs) {
  int t = threadIdx.x;
  int idx, b, p, P; float scale;
  if (t < 64)       { idx = 0; b = t >> 2;           p = t & 3;         P = 4;  scale = 1.f / 384.f; }
  else if (t < 208) { int u = t - 64;  idx = 1; b = u / 9;  p = u % 9;  P = 9;  scale = 1.f / 256.f; }
  else if (t < 464) { int u = t - 208; idx = 2; b = u >> 4; p = u & 15; P = 16; scale = 1.f / 192.f; }
  else return;
  const float* row = scores + (idx * BB + b) * 256 + p * P;
  float* orow = probs + (idx * BB + b) * 256 + p * P;
  float vals[16];
  float m = -1e30f;
  for (int i = 0; i < P; i++) { vals[i] = row[i] * scale; m = fmaxf(m, vals[i]); }
  float s = 0.f;
  for (int i = 0; i < P; i++) { vals[i] = expf(vals[i] - m); s += vals[i]; }
  float inv = 1.f / s;
  for (int i = 0; i < P; i++) orow[i] = vals[i] * inv;
}

// ---------------- PV + unstitch: block = (b, r); v/attn NHWC ----------------
template <int HS, int WS, int OH, int OW, int IDX>
__global__ __launch_bounds__(256) void pv_kernel(
    const unsigned short* __restrict__ v, const float* __restrict__ probs,
    unsigned short* __restrict__ attn) {
  constexpr int P = HS * WS;
  __shared__ unsigned short vl[HS * 96 * 72];  // [iq][col][c(64)+pad8]
  __shared__ float pl[P * P];
  int b = blockIdx.x / OH;
  int r = blockIdx.x % OH;
  const int tid = threadIdx.x;
  for (int u = tid; u < HS * 96 * 8; u += 256) {
    int iq = u / 768, w = (u >> 3) % 96, cg = u & 7;
    *(uint4*)(vl + (iq * 96 + w) * 72 + cg * 8) =
        *(const uint4*)(v + ((size_t)(b * HWSZ + (r * HS + iq) * WWW + w)) * CC + IDX * 64 + cg * 8);
  }
  if (tid < P * P) pl[tid] = probs[(IDX * BB + b) * 256 + tid];
  __syncthreads();
  for (int u = tid; u < HS * 96 * 8; u += 256) {
    int i = u / 768, w = (u >> 3) % 96, cg = u & 7;
    int j = w / OW, s = w - j * OW;
    int p = i * WS + j;
    float acc[8];
    #pragma unroll
    for (int m = 0; m < 8; ++m) acc[m] = 0.f;
    #pragma unroll
    for (int iq = 0; iq < HS; ++iq) {
      #pragma unroll
      for (int jq = 0; jq < WS; ++jq) {
        float pw = pl[p * P + iq * WS + jq];
        s8v vv = *(const s8v*)(vl + (iq * 96 + s * WS + jq) * 72 + cg * 8);
        #pragma unroll
        for (int m = 0; m < 8; ++m) acc[m] += pw * bf2f((unsigned short)vv[m]);
      }
    }
    uint4 ov;
    ov.x = (unsigned int)f2bf(acc[0]) | ((unsigned int)f2bf(acc[1]) << 16);
    ov.y = (unsigned int)f2bf(acc[2]) | ((unsigned int)f2bf(acc[3]) << 16);
    ov.z = (unsigned int)f2bf(acc[4]) | ((unsigned int)f2bf(acc[5]) << 16);
    ov.w = (unsigned int)f2bf(acc[6]) | ((unsigned int)f2bf(acc[7]) << 16);
    *(uint4*)(attn + ((size_t)(b * HWSZ + (i * OH + r) * WWW + w)) * CC + IDX * 64 + cg * 8) = ov;
  }
}

// ---------------- conv3x3 MFMA: A LDS (pad-40, dbuf), B global->reg; 6 barriers ----------------
__global__ __launch_bounds__(256) void conv_mfma_kernel(
    const unsigned short* __restrict__ attn, const unsigned short* __restrict__ wb9T,
    const float* __restrict__ b_out, unsigned short* __restrict__ ybf,
    float* __restrict__ bnsum, float* __restrict__ bnsqs) {
  __shared__ unsigned short al[2][3 * 98 * 40];  // [ky][w+halo][c32 + pad8]
  const int tid = threadIdx.x;
  const int h = blockIdx.x % HH;
  const int b = blockIdx.x / HH;
  const int lane = tid & 63, wid = tid >> 6;
  const int lr = lane & 15, hi8 = (lane >> 4) * 8, rowb = (lane >> 4) * 4;
  const int n0 = wid * 48;

  f32x4 acc[6][3];
  #pragma unroll
  for (int mt = 0; mt < 6; ++mt)
    #pragma unroll
    for (int nt = 0; nt < 3; ++nt) acc[mt][nt] = (f32x4){0.f, 0.f, 0.f, 0.f};

  auto stageA = [&](int chunk) {
    int c0 = chunk * 32;
    unsigned short* dst = al[chunk & 1];
    #pragma unroll
    for (int i = 0; i < 5; ++i) {
      int u = tid + i * 256;
      if (u < 1176) {
        int row = u / 392, rem = u % 392, wx = rem >> 2, qq = rem & 3;
        int hr = h + row - 1, w = wx - 1;
        uint4 val = make_uint4(0u, 0u, 0u, 0u);
        if (hr >= 0 && hr < HH && w >= 0 && w < WWW)
          val = *(const uint4*)(attn + ((size_t)(b * HWSZ + hr * WWW + w)) * CC + c0 + qq * 8);
        *(uint4*)(dst + (row * 98 + wx) * 40 + qq * 8) = val;
      }
    }
  };
  auto loadB = [&](int it2, s8v* dst) {
    int chunk = it2 / 9, sh = it2 % 9;
    const unsigned short* src = wb9T + (size_t)sh * CC * CC + chunk * 32 + hi8;
    #pragma unroll
    for (int nt = 0; nt < 3; ++nt)
      dst[nt] = *(const s8v*)(src + (size_t)(n0 + nt * 16 + lr) * CC);
  };

  s8v bcur[3], bnxt[3];
  stageA(0);
  loadB(0, bcur);
  __syncthreads();
  for (int it = 0; it < 54; ++it) {
    int chunk = it / 9, sh = it % 9, ky = sh / 3, kx = sh % 3;
    if (sh == 0 && chunk < 5) stageA(chunk + 1);
    if (it < 53) loadB(it + 1, bnxt);
    const unsigned short* A = al[chunk & 1];
    #pragma unroll
    for (int mt = 0; mt < 6; ++mt) {
      s8v a = *(const s8v*)(A + (ky * 98 + mt * 16 + lr + kx) * 40 + hi8);
      #pragma unroll
      for (int nt = 0; nt < 3; ++nt)
        acc[mt][nt] = __builtin_amdgcn_mfma_f32_16x16x32_bf16(a, bcur[nt], acc[mt][nt], 0, 0, 0);
    }
    #pragma unroll
    for (int nt = 0; nt < 3; ++nt) bcur[nt] = bnxt[nt];
    if (sh == 8) __syncthreads();
  }

  // epilogue: bias, bf16 y store (NCHW), BN partial sums
  float s1[3], s2[3];
  #pragma unroll
  for (int nt = 0; nt < 3; ++nt) { s1[nt] = 0.f; s2[nt] = 0.f; }
  #pragma unroll
  for (int nt = 0; nt < 3; ++nt) {
    int oc = n0 + nt * 16 + lr;
    float bias = b_out[oc];
    #pragma unroll
    for (int mt = 0; mt < 6; ++mt) {
      float v0 = acc[mt][nt][0] + bias;
      float v1 = acc[mt][nt][1] + bias;
      float v2 = acc[mt][nt][2] + bias;
      float v3 = acc[mt][nt][3] + bias;
      s1[nt] += v0 + v1 + v2 + v3;
      s2[nt] += v0 * v0 + v1 * v1 + v2 * v2 + v3 * v3;
      uint2 pk;
      pk.x = (unsigned int)f2bf(v0) | ((unsigned int)f2bf(v1) << 16);
      pk.y = (unsigned int)f2bf(v2) | ((unsigned int)f2bf(v3) << 16);
      *(uint2*)(ybf + ((size_t)(b * CC + oc)) * HWSZ + h * WWW + mt * 16 + rowb) = pk;
    }
  }
  #pragma unroll
  for (int nt = 0; nt < 3; ++nt) {
    s1[nt] += __shfl_down(s1[nt], 32);
    s1[nt] += __shfl_down(s1[nt], 16);
    s2[nt] += __shfl_down(s2[nt], 32);
    s2[nt] += __shfl_down(s2[nt], 16);
  }
  if (lane < 16) {
    #pragma unroll
    for (int nt = 0; nt < 3; ++nt) {
      atomicAdd(bnsum + n0 + nt * 16 + lane, s1[nt]);
      atomicAdd(bnsqs + n0 + nt * 16 + lane, s2[nt]);
    }
  }
}

// ---------------- BN finalize ----------------
__global__ void bnfin_kernel(const float* __restrict__ bnsum, const float* __restrict__ bnsqs,
                             const float* __restrict__ gamma, const float* __restrict__ beta,
                             float* __restrict__ scale, float* __restrict__ shift) {
  int c = threadIdx.x;
  if (c >= CC) return;
  const float n = 16.f * 9216.f;
  float mean = bnsum[c] / n;
  float var = bnsqs[c] / n - mean * mean;
  float inv = rsqrtf(var + 1e-5f);
  float sc = gamma[c] * inv;
  scale[c] = sc;
  shift[c] = beta[c] - mean * sc;
}

// ---------------- BN apply + LeakyReLU: ybf bf16 -> d_out fp32 ----------------
__global__ __launch_bounds__(256) void bnapply_kernel(const unsigned short* __restrict__ ybf,
                                                      float* __restrict__ y,
                                                      const float* __restrict__ scale,
                                                      const float* __restrict__ shift) {
  const int total8 = BB * CC * HWSZ / 8;
  for (int e = blockIdx.x * 256 + threadIdx.x; e < total8; e += gridDim.x * 256) {
    uint4 t = ((const uint4*)ybf)[e];
    const unsigned short* u = (const unsigned short*)&t;
    int oc = (e / (HWSZ / 8)) % CC;
    float sc = scale[oc], sh = shift[oc];
    float4 o0, o1;
    float w;
    w = bf2f(u[0]) * sc + sh; o0.x = w >= 0.f ? w : 0.2f * w;
    w = bf2f(u[1]) * sc + sh; o0.y = w >= 0.f ? w : 0.2f * w;
    w = bf2f(u[2]) * sc + sh; o0.z = w >= 0.f ? w : 0.2f * w;
    w = bf2f(u[3]) * sc + sh; o0.w = w >= 0.f ? w : 0.2f * w;
    w = bf2f(u[4]) * sc + sh; o1.x = w >= 0.f ? w : 0.2f * w;
    w = bf2f(u[5]) * sc + sh; o1.y = w >= 0.f ? w : 0.2f * w;
    w = bf2f(u[6]) * sc + sh; o1.z = w >= 0.f ? w : 0.2f * w;
    w = bf2f(u[7]) * sc + sh; o1.w = w >= 0.f ? w : 0.2f * w;
    ((float4*)y)[e * 2] = o0;
    ((float4*)y)[e * 2 + 1] = o1;
  }
}

extern "C" void kernel_launch(void* const* d_in, const int* in_sizes, int n_in,
                              void* d_out, int out_size, void* d_ws, size_t ws_size,
                              hipStream_t stream) {
  const float* x     = (const float*)d_in[0];
  const float* wq    = (const float*)d_in[1];
  const float* bq    = (const float*)d_in[2];
  const float* wk    = (const float*)d_in[3];
  const float* bk    = (const float*)d_in[4];
  const float* wv    = (const float*)d_in[5];
  const float* bv    = (const float*)d_in[6];
  const float* w_out = (const float*)d_in[7];
  const float* b_out = (const float*)d_in[8];
  const float* gamma = (const float*)d_in[9];
  const float* beta  = (const float*)d_in[10];

  char* ws = (char*)d_ws;
  const size_t TB = (size_t)BB * CC * HWSZ * sizeof(bf16);   // 56,623,104 B per tensor
  unsigned short* q    = (unsigned short*)(ws);               // NHWC bf16; later reused as ybf
  unsigned short* ybf  = q;                                   // y bf16 NCHW (q dead after scores)
  unsigned short* k    = (unsigned short*)(ws + TB);          // NHWC bf16
  unsigned short* v    = (unsigned short*)(ws + 2 * TB);      // NHWC bf16
  unsigned short* attn = (unsigned short*)(ws + 3 * TB);      // NHWC bf16; ALSO aliases xb
  unsigned short* xb   = attn;                                // x NHWC bf16 (dead before pv writes attn)
  unsigned short* wb9T = (unsigned short*)(ws + 4 * TB);      // [9][192][192] bf16
  unsigned short* wqkv = (unsigned short*)(ws + 4 * TB + 663552);  // [3][192][192] bf16
  float* scores = (float*)(ws + 4 * TB + 663552 + 221184);
  float* bnsum  = scores + 3 * BB * 256;
  float* bnsqs  = bnsum + CC;
  float* probs  = bnsqs + CC;
  float* scale  = probs + 3 * BB * 256;
  float* shift  = scale + CC;
  float* y = (float*)d_out;

  // zero scores + bn partials (contiguous)
  hipMemsetAsync(scores, 0, 49152 + 2 * CC * 4, stream);

  prep_w_kernel<<<(9 * CC * CC + 255) / 256, 256, 0, stream>>>(w_out, wb9T);
  prep_wqkv_kernel<<<(3 * CC * CC + 255) / 256, 256, 0, stream>>>(wq, wk, wv, wqkv);

  xcvt_kernel<<<BB * 144, 256, 0, stream>>>(x, xb);
  qkv_mfma_kernel<<<BB * HH * 3, 256, 0, stream>>>(xb, wqkv, bq, bk, bv, q, k, v);

  scores_kernel<2, 2, 48, 48, 0><<<BB * 16, 256, 0, stream>>>(q, k, scores);
  scores_kernel<3, 3, 32, 32, 1><<<BB * 16, 256, 0, stream>>>(q, k, scores);
  scores_kernel<4, 4, 24, 24, 2><<<BB * 16, 256, 0, stream>>>(q, k, scores);

  softmax_kernel<<<1, 512, 0, stream>>>(scores, probs);

  pv_kernel<2, 2, 48, 48, 0><<<BB * 48, 256, 0, stream>>>(v, probs, attn);
  pv_kernel<3, 3, 32, 32, 1><<<BB * 32, 256, 0, stream>>>(v, probs, attn);
  pv_kernel<4, 4, 24, 24, 2><<<BB * 24, 256, 0, stream>>>(v, probs, attn);

  conv_mfma_kernel<<<BB * HH, 256, 0, stream>>>(attn, wb9T, b_out, ybf, bnsum, bnsqs);

  bnfin_kernel<<<1, 256, 0, stream>>>(bnsum, bnsqs, gamma, beta, scale, shift);
  bnapply_kernel<<<2048, 256, 0, stream>>>(ybf, y, scale, shift);
}

// Round 7
// 505.407 us; speedup vs baseline: 11.3696x; 1.0920x over previous
//
#include <hip/hip_runtime.h>
#include <hip/hip_bf16.h>

#define BB 16
#define CC 192
#define HH 96
#define WWW 96
#define HWSZ 9216
#define DKC 64

typedef __hip_bfloat16 bf16;
typedef __attribute__((ext_vector_type(8))) short s8v;
typedef __attribute__((ext_vector_type(4))) float f32x4;

__device__ __forceinline__ float bf2f(unsigned short u) {
  union { unsigned int i; float f; } x; x.i = ((unsigned int)u) << 16; return x.f;
}
__device__ __forceinline__ unsigned short f2bf(float f) {
  union { __hip_bfloat16 h; unsigned short u; } c; c.h = __float2bfloat16(f); return c.u;
}

// ---------------- prep: w_out [oc][c][ky][kx] -> wb9T [sh][oc][c] bf16 ----------------
__global__ __launch_bounds__(256) void prep_w_kernel(const float* __restrict__ w_out,
                                                     unsigned short* __restrict__ wb9T) {
  int e = blockIdx.x * 256 + threadIdx.x;
  if (e >= 9 * CC * CC) return;
  int c = e % CC;
  int oc = (e / CC) % CC;
  int sh = e / (CC * CC);
  wb9T[e] = f2bf(w_out[((size_t)(oc * CC + c)) * 9 + sh]);
}

// ---------------- prep: wq/wk/wv fp32 -> wqkv [sel][oc][c] bf16 ----------------
__global__ __launch_bounds__(256) void prep_wqkv_kernel(
    const float* __restrict__ wq, const float* __restrict__ wk, const float* __restrict__ wv,
    unsigned short* __restrict__ wqkv) {
  int e = blockIdx.x * 256 + threadIdx.x;
  if (e >= 3 * CC * CC) return;
  int sel = e / (CC * CC), r = e % (CC * CC);
  const float* w = sel == 0 ? wq : sel == 1 ? wk : wv;
  wqkv[e] = f2bf(w[r]);
}

// ---------------- x: NCHW fp32 -> NHWC bf16 ----------------
__global__ __launch_bounds__(256) void xcvt_kernel(const float* __restrict__ x,
                                                   unsigned short* __restrict__ xb) {
  __shared__ float xt[CC][65];
  int b = blockIdx.x / 144, tile = blockIdx.x % 144;
  int pix0 = tile * 64;
  const float* xsrc = x + (size_t)b * CC * HWSZ + pix0;
  for (int e = threadIdx.x; e < CC * 16; e += 256) {
    int c = e >> 4, seg = e & 15;
    float4 t4 = *(const float4*)(xsrc + (size_t)c * HWSZ + seg * 4);
    xt[c][seg * 4 + 0] = t4.x; xt[c][seg * 4 + 1] = t4.y;
    xt[c][seg * 4 + 2] = t4.z; xt[c][seg * 4 + 3] = t4.w;
  }
  __syncthreads();
  unsigned short* dst = xb + ((size_t)(b * HWSZ + pix0)) * CC;
  for (int e = threadIdx.x; e < 24 * 64; e += 256) {
    int cg = e >> 6, p = e & 63;
    uint4 ov;
    unsigned short* ou = (unsigned short*)&ov;
    #pragma unroll
    for (int j = 0; j < 8; ++j) ou[j] = f2bf(xt[cg * 8 + j][p]);
    *(uint4*)(dst + (size_t)p * CC + cg * 8) = ov;
  }
}

// ---------------- QKV via MFMA: A LDS dbuf (T14 split), B ring-3 in regs ----------------
__global__ __launch_bounds__(256) void qkv_mfma_kernel(
    const unsigned short* __restrict__ xb, const unsigned short* __restrict__ wqkv,
    const float* __restrict__ bq, const float* __restrict__ bk, const float* __restrict__ bv,
    unsigned short* __restrict__ q, unsigned short* __restrict__ k,
    unsigned short* __restrict__ v) {
  __shared__ unsigned short al[2][96 * 40];   // [pix][c32 + pad8]
  __shared__ unsigned short vt[48 * 224];     // half-size transpose buffer (2-pass)
  const int tid = threadIdx.x;
  const int bid = (blockIdx.x & 7) * 576 + (blockIdx.x >> 3);  // XCD swizzle (4608/8=576)
  const int sel = bid % 3;
  const int h = (bid / 3) % HH;
  const int b = bid / (3 * HH);
  const int lane = tid & 63, wid = tid >> 6;
  const int lr = lane & 15, hi8 = (lane >> 4) * 8, rowb = (lane >> 4) * 4;
  const int n0 = wid * 48;
  const unsigned short* xrow = xb + ((size_t)(b * HWSZ + h * WWW)) * CC;
  const unsigned short* wsel = wqkv + (size_t)sel * CC * CC;

  f32x4 acc[6][3];
  #pragma unroll
  for (int mt = 0; mt < 6; ++mt)
    #pragma unroll
    for (int nt = 0; nt < 3; ++nt) acc[mt][nt] = (f32x4){0.f, 0.f, 0.f, 0.f};

  auto loadB = [&](int ck, s8v (&dst)[3]) {
    const unsigned short* src = wsel + ck * 32 + hi8;
    #pragma unroll
    for (int nt = 0; nt < 3; ++nt)
      dst[nt] = *(const s8v*)(src + (size_t)(n0 + nt * 16 + lr) * CC);
  };

  s8v br0[3], br1[3], br2[3];
  // prologue: stage chunk 0, fill B ring
  {
    uint4 a0 = *(const uint4*)(xrow + (size_t)(tid >> 2) * CC + (tid & 3) * 8);
    uint4 a1;
    int u1 = tid + 256;
    if (u1 < 384) a1 = *(const uint4*)(xrow + (size_t)(u1 >> 2) * CC + (u1 & 3) * 8);
    loadB(0, br0); loadB(1, br1); loadB(2, br2);
    *(uint4*)(al[0] + (tid >> 2) * 40 + (tid & 3) * 8) = a0;
    if (u1 < 384) *(uint4*)(al[0] + (u1 >> 2) * 40 + (u1 & 3) * 8) = a1;
  }
  __syncthreads();

  auto qstep = [&](int ck, s8v (&slot)[3]) {
    // early: A global loads for ck+1
    uint4 ar0, ar1;
    int u1 = tid + 256;
    if (ck < 5) {
      ar0 = *(const uint4*)(xrow + (size_t)(tid >> 2) * CC + (ck + 1) * 32 + (tid & 3) * 8);
      if (u1 < 384)
        ar1 = *(const uint4*)(xrow + (size_t)(u1 >> 2) * CC + (ck + 1) * 32 + (u1 & 3) * 8);
    }
    const unsigned short* A = al[ck & 1];
    s8v a[6];
    #pragma unroll
    for (int mt = 0; mt < 6; ++mt)
      a[mt] = *(const s8v*)(A + (mt * 16 + lr) * 40 + hi8);
    #pragma unroll
    for (int mt = 0; mt < 6; ++mt)
      #pragma unroll
      for (int nt = 0; nt < 3; ++nt)
        acc[mt][nt] = __builtin_amdgcn_mfma_f32_16x16x32_bf16(a[mt], slot[nt], acc[mt][nt], 0, 0, 0);
    if (ck + 3 < 6) loadB(ck + 3, slot);
    // late: A LDS writes for ck+1
    if (ck < 5) {
      unsigned short* dstA = al[(ck + 1) & 1];
      *(uint4*)(dstA + (tid >> 2) * 40 + (tid & 3) * 8) = ar0;
      if (u1 < 384) *(uint4*)(dstA + (u1 >> 2) * 40 + (u1 & 3) * 8) = ar1;
    }
    __syncthreads();
  };
  qstep(0, br0); qstep(1, br1); qstep(2, br2);
  qstep(3, br0); qstep(4, br1); qstep(5, br2);

  // epilogue: bias, 2-pass LDS transpose, NHWC store
  const float* bsel = (sel == 0 ? bq : sel == 1 ? bk : bv);
  float bias[3];
  #pragma unroll
  for (int nt = 0; nt < 3; ++nt) bias[nt] = bsel[n0 + nt * 16 + lr];
  unsigned short* dst = (sel == 0 ? q : sel == 1 ? k : v) + ((size_t)(b * HWSZ + h * WWW)) * CC;
  #pragma unroll
  for (int pass = 0; pass < 2; ++pass) {
    if (pass) __syncthreads();
    #pragma unroll
    for (int mt2 = 0; mt2 < 3; ++mt2) {
      #pragma unroll
      for (int nt = 0; nt < 3; ++nt)
        #pragma unroll
        for (int i = 0; i < 4; ++i)
          vt[(mt2 * 16 + rowb + i) * 224 + n0 + nt * 16 + lr] =
              f2bf(acc[pass * 3 + mt2][nt][i] + bias[nt]);
    }
    __syncthreads();
    for (int e = tid; e < 48 * 24; e += 256) {
      int p = e % 48, cg = e / 48;
      *(uint4*)(dst + (size_t)(pass * 48 + p) * CC + cg * 8) = *(uint4*)(vt + p * 224 + cg * 8);
    }
  }
}

// ---------------- scores: P x P dots over D, NHWC q/k ----------------
template <int HS, int WS, int OH, int OW, int IDX>
__global__ __launch_bounds__(256) void scores_kernel(
    const unsigned short* __restrict__ q, const unsigned short* __restrict__ k,
    float* __restrict__ scores) {
  constexpr int P = HS * WS;
  constexpr int PAIRS = P * P;
  constexpr int NB = 16;
  constexpr int NSUB = (256 / PAIRS) < 1 ? 1 : (256 / PAIRS);
  __shared__ float qt[128][P + 1];
  __shared__ float kt[128][P + 1];
  int b = blockIdx.x / NB;
  int blk = blockIdx.x % NB;
  const unsigned short* qb = q + (size_t)b * HWSZ * CC;
  const unsigned short* kb = k + (size_t)b * HWSZ * CC;
  int pr = threadIdx.x % PAIRS;
  int sub = threadIdx.x / PAIRS;
  int pi = pr / P, qi = pr % P;
  float acc = 0.f;
  for (int rs0 = blk * 2; rs0 < OH * OW; rs0 += NB * 2) {
    if (threadIdx.x < 16 * P) {
      int cg = threadIdx.x & 7;
      int t2 = threadIdx.x >> 3;
      int pp = t2 % P, rs2 = t2 / P;
      int rs = rs0 + rs2;
      int r = rs / OW, s = rs % OW;
      int i = pp / WS, j = pp % WS;
      int pixel = (r * HS + i) * WWW + s * WS + j;
      uint4 qv = *(const uint4*)(qb + (size_t)pixel * CC + IDX * 64 + cg * 8);
      uint4 kv = *(const uint4*)(kb + (size_t)pixel * CC + IDX * 64 + cg * 8);
      const unsigned short* qu = (const unsigned short*)&qv;
      const unsigned short* ku = (const unsigned short*)&kv;
      #pragma unroll
      for (int m = 0; m < 8; ++m) {
        qt[rs2 * 64 + cg * 8 + m][pp] = bf2f(qu[m]);
        kt[rs2 * 64 + cg * 8 + m][pp] = bf2f(ku[m]);
      }
    }
    __syncthreads();
    if (sub < NSUB) {
      #pragma unroll 4
      for (int pos = sub; pos < 128; pos += NSUB)
        acc += qt[pos][pi] * kt[pos][qi];
    }
    __syncthreads();
  }
  if (sub < NSUB) atomicAdd(scores + ((IDX * BB + b) * 256 + pr), acc);
}

// ---------------- softmax over P ----------------
__global__ void softmax_kernel(const float* __restrict__ scores, float* __restrict__ probs) {
  int t = threadIdx.x;
  int idx, b, p, P; float scale;
  if (t < 64)       { idx = 0; b = t >> 2;           p = t & 3;         P = 4;  scale = 1.f / 384.f; }
  else if (t < 208) { int u = t - 64;  idx = 1; b = u / 9;  p = u % 9;  P = 9;  scale = 1.f / 256.f; }
  else if (t < 464) { int u = t - 208; idx = 2; b = u >> 4; p = u & 15; P = 16; scale = 1.f / 192.f; }
  else return;
  const float* row = scores + (idx * BB + b) * 256 + p * P;
  float* orow = probs + (idx * BB + b) * 256 + p * P;
  float vals[16];
  float m = -1e30f;
  for (int i = 0; i < P; i++) { vals[i] = row[i] * scale; m = fmaxf(m, vals[i]); }
  float s = 0.f;
  for (int i = 0; i < P; i++) { vals[i] = expf(vals[i] - m); s += vals[i]; }
  float inv = 1.f / s;
  for (int i = 0; i < P; i++) orow[i] = vals[i] * inv;
}

// ---------------- PV + unstitch: block = (b, r); v/attn NHWC ----------------
template <int HS, int WS, int OH, int OW, int IDX>
__global__ __launch_bounds__(256) void pv_kernel(
    const unsigned short* __restrict__ v, const float* __restrict__ probs,
    unsigned short* __restrict__ attn) {
  constexpr int P = HS * WS;
  __shared__ unsigned short vl[HS * 96 * 72];  // [iq][col][c(64)+pad8]
  __shared__ float pl[P * P];
  int b = blockIdx.x / OH;
  int r = blockIdx.x % OH;
  const int tid = threadIdx.x;
  for (int u = tid; u < HS * 96 * 8; u += 256) {
    int iq = u / 768, w = (u >> 3) % 96, cg = u & 7;
    *(uint4*)(vl + (iq * 96 + w) * 72 + cg * 8) =
        *(const uint4*)(v + ((size_t)(b * HWSZ + (r * HS + iq) * WWW + w)) * CC + IDX * 64 + cg * 8);
  }
  if (tid < P * P) pl[tid] = probs[(IDX * BB + b) * 256 + tid];
  __syncthreads();
  for (int u = tid; u < HS * 96 * 8; u += 256) {
    int i = u / 768, w = (u >> 3) % 96, cg = u & 7;
    int j = w / OW, s = w - j * OW;
    int p = i * WS + j;
    float acc[8];
    #pragma unroll
    for (int m = 0; m < 8; ++m) acc[m] = 0.f;
    #pragma unroll
    for (int iq = 0; iq < HS; ++iq) {
      #pragma unroll
      for (int jq = 0; jq < WS; ++jq) {
        float pw = pl[p * P + iq * WS + jq];
        s8v vv = *(const s8v*)(vl + (iq * 96 + s * WS + jq) * 72 + cg * 8);
        #pragma unroll
        for (int m = 0; m < 8; ++m) acc[m] += pw * bf2f((unsigned short)vv[m]);
      }
    }
    uint4 ov;
    ov.x = (unsigned int)f2bf(acc[0]) | ((unsigned int)f2bf(acc[1]) << 16);
    ov.y = (unsigned int)f2bf(acc[2]) | ((unsigned int)f2bf(acc[3]) << 16);
    ov.z = (unsigned int)f2bf(acc[4]) | ((unsigned int)f2bf(acc[5]) << 16);
    ov.w = (unsigned int)f2bf(acc[6]) | ((unsigned int)f2bf(acc[7]) << 16);
    *(uint4*)(attn + ((size_t)(b * HWSZ + (i * OH + r) * WWW + w)) * CC + IDX * 64 + cg * 8) = ov;
  }
}

// ---------------- conv3x3 MFMA: A LDS dbuf (T14 split), B ring-3; 6 barriers ----------------
__global__ __launch_bounds__(256) void conv_mfma_kernel(
    const unsigned short* __restrict__ attn, const unsigned short* __restrict__ wb9T,
    const float* __restrict__ b_out, unsigned short* __restrict__ ybf,
    float* __restrict__ bnsum, float* __restrict__ bnsqs) {
  __shared__ unsigned short al[2][3 * 98 * 40];  // [ky][w+halo][c32 + pad8]
  const int tid = threadIdx.x;
  const int bid = (blockIdx.x & 7) * 192 + (blockIdx.x >> 3);  // XCD swizzle (1536/8=192)
  const int h = bid % HH;
  const int b = bid / HH;
  const int lane = tid & 63, wid = tid >> 6;
  const int lr = lane & 15, hi8 = (lane >> 4) * 8, rowb = (lane >> 4) * 4;
  const int n0 = wid * 48;

  f32x4 acc[6][3];
  #pragma unroll
  for (int mt = 0; mt < 6; ++mt)
    #pragma unroll
    for (int nt = 0; nt < 3; ++nt) acc[mt][nt] = (f32x4){0.f, 0.f, 0.f, 0.f};

  uint4 aregs[5];
  auto stageA_LOAD = [&](int chunk) {
    int c0 = chunk * 32;
    #pragma unroll
    for (int i = 0; i < 5; ++i) {
      int u = tid + i * 256;
      if (u < 1176) {
        int row = u / 392, rem = u % 392, wx = rem >> 2, qq = rem & 3;
        int hr = h + row - 1, w = wx - 1;
        uint4 val = make_uint4(0u, 0u, 0u, 0u);
        if (hr >= 0 && hr < HH && w >= 0 && w < WWW)
          val = *(const uint4*)(attn + ((size_t)(b * HWSZ + hr * WWW + w)) * CC + c0 + qq * 8);
        aregs[i] = val;
      }
    }
  };
  auto stageA_WRITE = [&](int chunk) {
    unsigned short* dst = al[chunk & 1];
    #pragma unroll
    for (int i = 0; i < 5; ++i) {
      int u = tid + i * 256;
      if (u < 1176) {
        int row = u / 392, rem = u % 392, wx = rem >> 2, qq = rem & 3;
        *(uint4*)(dst + (row * 98 + wx) * 40 + qq * 8) = aregs[i];
      }
    }
  };
  auto loadB = [&](int it2, s8v (&dst)[3]) {
    int chunk = it2 / 9, sh = it2 % 9;
    const unsigned short* src = wb9T + (size_t)sh * CC * CC + chunk * 32 + hi8;
    #pragma unroll
    for (int nt = 0; nt < 3; ++nt)
      dst[nt] = *(const s8v*)(src + (size_t)(n0 + nt * 16 + lr) * CC);
  };

  s8v br0[3], br1[3], br2[3];
  stageA_LOAD(0);
  stageA_WRITE(0);
  loadB(0, br0); loadB(1, br1); loadB(2, br2);
  __syncthreads();

  auto step = [&](int it, s8v (&slot)[3]) {
    int chunk = it / 9, sh = it % 9, ky = sh / 3, kx = sh % 3;
    if (sh == 0 && chunk < 5) stageA_LOAD(chunk + 1);
    const unsigned short* A = al[chunk & 1];
    s8v a[6];
    #pragma unroll
    for (int mt = 0; mt < 6; ++mt)
      a[mt] = *(const s8v*)(A + (ky * 98 + mt * 16 + lr + kx) * 40 + hi8);
    #pragma unroll
    for (int mt = 0; mt < 6; ++mt)
      #pragma unroll
      for (int nt = 0; nt < 3; ++nt)
        acc[mt][nt] = __builtin_amdgcn_mfma_f32_16x16x32_bf16(a[mt], slot[nt], acc[mt][nt], 0, 0, 0);
    if (it + 3 < 54) loadB(it + 3, slot);
    if (sh == 7 && chunk < 5) stageA_WRITE(chunk + 1);
    if (sh == 8) __syncthreads();
  };
  for (int it3 = 0; it3 < 54; it3 += 3) {
    step(it3 + 0, br0);
    step(it3 + 1, br1);
    step(it3 + 2, br2);
  }

  // epilogue: bias, bf16 y store (NCHW), BN partial sums
  float s1[3], s2[3];
  #pragma unroll
  for (int nt = 0; nt < 3; ++nt) { s1[nt] = 0.f; s2[nt] = 0.f; }
  #pragma unroll
  for (int nt = 0; nt < 3; ++nt) {
    int oc = n0 + nt * 16 + lr;
    float bias = b_out[oc];
    #pragma unroll
    for (int mt = 0; mt < 6; ++mt) {
      float v0 = acc[mt][nt][0] + bias;
      float v1 = acc[mt][nt][1] + bias;
      float v2 = acc[mt][nt][2] + bias;
      float v3 = acc[mt][nt][3] + bias;
      s1[nt] += v0 + v1 + v2 + v3;
      s2[nt] += v0 * v0 + v1 * v1 + v2 * v2 + v3 * v3;
      uint2 pk;
      pk.x = (unsigned int)f2bf(v0) | ((unsigned int)f2bf(v1) << 16);
      pk.y = (unsigned int)f2bf(v2) | ((unsigned int)f2bf(v3) << 16);
      *(uint2*)(ybf + ((size_t)(b * CC + oc)) * HWSZ + h * WWW + mt * 16 + rowb) = pk;
    }
  }
  #pragma unroll
  for (int nt = 0; nt < 3; ++nt) {
    s1[nt] += __shfl_down(s1[nt], 32);
    s1[nt] += __shfl_down(s1[nt], 16);
    s2[nt] += __shfl_down(s2[nt], 32);
    s2[nt] += __shfl_down(s2[nt], 16);
  }
  if (lane < 16) {
    #pragma unroll
    for (int nt = 0; nt < 3; ++nt) {
      atomicAdd(bnsum + n0 + nt * 16 + lane, s1[nt]);
      atomicAdd(bnsqs + n0 + nt * 16 + lane, s2[nt]);
    }
  }
}

// ---------------- BN finalize ----------------
__global__ void bnfin_kernel(const float* __restrict__ bnsum, const float* __restrict__ bnsqs,
                             const float* __restrict__ gamma, const float* __restrict__ beta,
                             float* __restrict__ scale, float* __restrict__ shift) {
  int c = threadIdx.x;
  if (c >= CC) return;
  const float n = 16.f * 9216.f;
  float mean = bnsum[c] / n;
  float var = bnsqs[c] / n - mean * mean;
  float inv = rsqrtf(var + 1e-5f);
  float sc = gamma[c] * inv;
  scale[c] = sc;
  shift[c] = beta[c] - mean * sc;
}

// ---------------- BN apply + LeakyReLU: ybf bf16 -> d_out fp32 ----------------
__global__ __launch_bounds__(256) void bnapply_kernel(const unsigned short* __restrict__ ybf,
                                                      float* __restrict__ y,
                                                      const float* __restrict__ scale,
                                                      const float* __restrict__ shift) {
  const int total8 = BB * CC * HWSZ / 8;
  for (int e = blockIdx.x * 256 + threadIdx.x; e < total8; e += gridDim.x * 256) {
    uint4 t = ((const uint4*)ybf)[e];
    const unsigned short* u = (const unsigned short*)&t;
    int oc = (e / (HWSZ / 8)) % CC;
    float sc = scale[oc], sh = shift[oc];
    float4 o0, o1;
    float w;
    w = bf2f(u[0]) * sc + sh; o0.x = w >= 0.f ? w : 0.2f * w;
    w = bf2f(u[1]) * sc + sh; o0.y = w >= 0.f ? w : 0.2f * w;
    w = bf2f(u[2]) * sc + sh; o0.z = w >= 0.f ? w : 0.2f * w;
    w = bf2f(u[3]) * sc + sh; o0.w = w >= 0.f ? w : 0.2f * w;
    w = bf2f(u[4]) * sc + sh; o1.x = w >= 0.f ? w : 0.2f * w;
    w = bf2f(u[5]) * sc + sh; o1.y = w >= 0.f ? w : 0.2f * w;
    w = bf2f(u[6]) * sc + sh; o1.z = w >= 0.f ? w : 0.2f * w;
    w = bf2f(u[7]) * sc + sh; o1.w = w >= 0.f ? w : 0.2f * w;
    ((float4*)y)[e * 2] = o0;
    ((float4*)y)[e * 2 + 1] = o1;
  }
}

extern "C" void kernel_launch(void* const* d_in, const int* in_sizes, int n_in,
                              void* d_out, int out_size, void* d_ws, size_t ws_size,
                              hipStream_t stream) {
  const float* x     = (const float*)d_in[0];
  const float* wq    = (const float*)d_in[1];
  const float* bq    = (const float*)d_in[2];
  const float* wk    = (const float*)d_in[3];
  const float* bk    = (const float*)d_in[4];
  const float* wv    = (const float*)d_in[5];
  const float* bv    = (const float*)d_in[6];
  const float* w_out = (const float*)d_in[7];
  const float* b_out = (const float*)d_in[8];
  const float* gamma = (const float*)d_in[9];
  const float* beta  = (const float*)d_in[10];

  char* ws = (char*)d_ws;
  const size_t TB = (size_t)BB * CC * HWSZ * sizeof(bf16);   // 56,623,104 B per tensor
  unsigned short* q    = (unsigned short*)(ws);               // NHWC bf16; later reused as ybf
  unsigned short* ybf  = q;                                   // y bf16 NCHW (q dead after scores)
  unsigned short* k    = (unsigned short*)(ws + TB);          // NHWC bf16
  unsigned short* v    = (unsigned short*)(ws + 2 * TB);      // NHWC bf16
  unsigned short* attn = (unsigned short*)(ws + 3 * TB);      // NHWC bf16; ALSO aliases xb
  unsigned short* xb   = attn;                                // x NHWC bf16 (dead before pv writes attn)
  unsigned short* wb9T = (unsigned short*)(ws + 4 * TB);      // [9][192][192] bf16
  unsigned short* wqkv = (unsigned short*)(ws + 4 * TB + 663552);  // [3][192][192] bf16
  float* scores = (float*)(ws + 4 * TB + 663552 + 221184);
  float* bnsum  = scores + 3 * BB * 256;
  float* bnsqs  = bnsum + CC;
  float* probs  = bnsqs + CC;
  float* scale  = probs + 3 * BB * 256;
  float* shift  = scale + CC;
  float* y = (float*)d_out;

  // zero scores + bn partials (contiguous)
  hipMemsetAsync(scores, 0, 49152 + 2 * CC * 4, stream);

  prep_w_kernel<<<(9 * CC * CC + 255) / 256, 256, 0, stream>>>(w_out, wb9T);
  prep_wqkv_kernel<<<(3 * CC * CC + 255) / 256, 256, 0, stream>>>(wq, wk, wv, wqkv);

  xcvt_kernel<<<BB * 144, 256, 0, stream>>>(x, xb);
  qkv_mfma_kernel<<<BB * HH * 3, 256, 0, stream>>>(xb, wqkv, bq, bk, bv, q, k, v);

  scores_kernel<2, 2, 48, 48, 0><<<BB * 16, 256, 0, stream>>>(q, k, scores);
  scores_kernel<3, 3, 32, 32, 1><<<BB * 16, 256, 0, stream>>>(q, k, scores);
  scores_kernel<4, 4, 24, 24, 2><<<BB * 16, 256, 0, stream>>>(q, k, scores);

  softmax_kernel<<<1, 512, 0, stream>>>(scores, probs);

  pv_kernel<2, 2, 48, 48, 0><<<BB * 48, 256, 0, stream>>>(v, probs, attn);
  pv_kernel<3, 3, 32, 32, 1><<<BB * 32, 256, 0, stream>>>(v, probs, attn);
  pv_kernel<4, 4, 24, 24, 2><<<BB * 24, 256, 0, stream>>>(v, probs, attn);

  conv_mfma_kernel<<<BB * HH, 256, 0, stream>>>(attn, wb9T, b_out, ybf, bnsum, bnsqs);

  bnfin_kernel<<<1, 256, 0, stream>>>(bnsum, bnsqs, gamma, beta, scale, shift);
  bnapply_kernel<<<2048, 256, 0, stream>>>(ybf, y, scale, shift);
}